// Round 3
// baseline (3379.837 us; speedup 1.0000x reference)
//
#include <hip/hip_runtime.h>
#include <hip/hip_bf16.h>
#include <math.h>

#define NNODE 65536
#define NBAT  16384
#define NP    5
#define DT    0.1f
#define EPS   1e-5f

typedef __attribute__((ext_vector_type(8))) short short8;
typedef __attribute__((ext_vector_type(4))) float floatx4;

union S8U { short8 s; unsigned int u[4]; };

__device__ __forceinline__ float swishf(float x) {
    return x / (1.f + __expf(-x));
}
__device__ __forceinline__ float asf(unsigned int u) {
    union { unsigned int u; float f; } x; x.u = u; return x.f;
}
__device__ __forceinline__ unsigned short f2b(float f) {
    union { float f; unsigned int u; } x; x.f = f;
    unsigned int r = x.u + 0x7fff + ((x.u >> 16) & 1);
    return (unsigned short)(r >> 16);
}
__device__ __forceinline__ unsigned int pk2(float a, float b) {
    __hip_bfloat162 h = __float22bfloat162_rn(make_float2(a, b));
    union { __hip_bfloat162 h; unsigned int u; } x; x.h = h; return x.u;
}

// padded fragment chunk offset (in shorts): chunk(w, g, row15), g,row15 in 0..15
#define CHP(w, g, r15) ((((w) * 272) + (g) * 17 + (r15)) * 8)
// linear fragment chunk offset (in shorts)
#define CHL(w, g, r15) ((((w) * 256) + (g) * 16 + (r15)) * 8)

// ---------- weight prep: fp32 [L][rows][ldn] -> bf16 fragment-linear ----------
// dst chunk order: [l][t][ks][lane][8j]; element = src[koff + k][n], n = t*16+lm,
// p = ks*32+lq*8+j, k = perm ? (p&7)*16 + (p>>3) : p
__global__ __launch_bounds__(256) void prep_frag(
    const float* __restrict__ src, unsigned short* __restrict__ dst,
    int ldn, int koff, int NT, int lstride, int perm, int total)
{
    int i = blockIdx.x * 256 + threadIdx.x;
    if (i >= total) return;
    int nper = NT << 11;
    int l = i / nper;
    int r0 = i - l * nper;
    int t = r0 >> 11;
    int ks = (r0 >> 9) & 3;
    int lane = (r0 >> 3) & 63;
    int j = r0 & 7;
    int lm = lane & 15, lq = lane >> 4;
    int p = ks * 32 + lq * 8 + j;
    int k = perm ? ((p & 7) * 16 + (p >> 3)) : p;
    int n = t * 16 + lm;
    dst[i] = f2b(src[(size_t)l * lstride + (size_t)(koff + k) * ldn + n]);
}

// ---------- node scalars + stats/meanrstd init ----------
__global__ __launch_bounds__(256) void node_init(
    const float* __restrict__ inp, const float* __restrict__ cp,
    float* __restrict__ u, float* __restrict__ posx, float* __restrict__ posy,
    float* __restrict__ stats, float* __restrict__ mr)
{
    int n = blockIdx.x * 256 + threadIdx.x;
    int b = n >> 14, r = n & 16383;
    int a = r >> 7, c = r & 127;
    u[n] = inp[b * 3 * NBAT + r];
    posx[n] = (a * (1.f / 127.f)) * cp[b * NP + 1];
    posy[n] = (c * (1.f / 127.f)) * cp[b * NP + 0];
    if (n < 1024) {
        stats[n] = 0.f;
        mr[n] = ((n >> 7) & 1) ? 1.f : 0.f;   // mean 0, rstd 1 (identity)
    }
}

// ---------- embedding: 8 -> 128 (VALU) -> 128 (MFMA); f written p-space fp32 ----------
__global__ __launch_bounds__(256) void embed_mfma(
    const float* __restrict__ u, const float* __restrict__ posx,
    const float* __restrict__ posy, const float* __restrict__ cp,
    const float* __restrict__ W1, const float* __restrict__ b1,
    const unsigned short* __restrict__ W2F, const float* __restrict__ b2,
    float* __restrict__ f)
{
    __shared__ unsigned short lA[4 * 272 * 8];
    __shared__ unsigned short lB[2048 * 8];
    int tid = threadIdx.x;
    int block0 = blockIdx.x * 64;
    // stage 1: hid1 = swish(e @ W1 + b1), write bf16 fragments
    {
        int r = tid >> 2, p4 = tid & 3;
        int n = block0 + r;
        int b = n >> 14;
        float e8[8];
        e8[0] = u[n]; e8[1] = posx[n]; e8[2] = posy[n];
#pragma unroll
        for (int p = 0; p < 5; p++) e8[3 + p] = cp[b * NP + p];
        float a32[32];
        const float4* b4 = (const float4*)(b1 + p4 * 32);
#pragma unroll
        for (int q = 0; q < 8; q++) {
            float4 bv = b4[q];
            a32[q * 4 + 0] = bv.x; a32[q * 4 + 1] = bv.y;
            a32[q * 4 + 2] = bv.z; a32[q * 4 + 3] = bv.w;
        }
#pragma unroll
        for (int i = 0; i < 8; i++) {
            const float4* w4 = (const float4*)(W1 + i * 128 + p4 * 32);
            float ev = e8[i];
#pragma unroll
            for (int q = 0; q < 8; q++) {
                float4 wv = w4[q];
                a32[q * 4 + 0] += ev * wv.x; a32[q * 4 + 1] += ev * wv.y;
                a32[q * 4 + 2] += ev * wv.z; a32[q * 4 + 3] += ev * wv.w;
            }
        }
#pragma unroll
        for (int j = 0; j < 4; j++) {
            S8U o;
#pragma unroll
            for (int q = 0; q < 4; q++)
                o.u[q] = pk2(swishf(a32[j * 8 + 2 * q]), swishf(a32[j * 8 + 2 * q + 1]));
            *(short8*)(lA + CHP(r >> 4, p4 * 4 + j, r & 15)) = o.s;
        }
    }
#pragma unroll
    for (int i = 0; i < 8; i++)
        *(short8*)(lB + (tid + i * 256) * 8) = *(const short8*)(W2F + (tid + i * 256) * 8);
    __syncthreads();
    int w = tid >> 6, lane = tid & 63, lm = lane & 15, lq = lane >> 4;
    floatx4 acc[8];
#pragma unroll
    for (int t = 0; t < 8; t++) acc[t] = (floatx4)(0.f);
#pragma unroll
    for (int ks = 0; ks < 4; ks++) {
        short8 a = *(const short8*)(lA + CHP(w, ks * 4 + lq, lm));
#pragma unroll
        for (int t = 0; t < 8; t++) {
            short8 bf = *(const short8*)(lB + ((t * 4 + ks) * 64 + lane) * 8);
            acc[t] = __builtin_amdgcn_mfma_f32_16x16x32_bf16(a, bf, acc[t], 0, 0, 0);
        }
    }
    float bias2[8];
#pragma unroll
    for (int t = 0; t < 8; t++) bias2[t] = b2[t * 16 + lm];
#pragma unroll
    for (int r = 0; r < 4; r++) {
        int nd = block0 + w * 16 + lq * 4 + r;
        float4 v0, v1;
        v0.x = swishf(acc[0][r] + bias2[0]); v0.y = swishf(acc[1][r] + bias2[1]);
        v0.z = swishf(acc[2][r] + bias2[2]); v0.w = swishf(acc[3][r] + bias2[3]);
        v1.x = swishf(acc[4][r] + bias2[4]); v1.y = swishf(acc[5][r] + bias2[5]);
        v1.z = swishf(acc[6][r] + bias2[6]); v1.w = swishf(acc[7][r] + bias2[7]);
        *(float4*)(f + (size_t)nd * 128 + lm * 8) = v0;
        *(float4*)(f + (size_t)nd * 128 + lm * 8 + 4) = v1;
    }
}

// ---------- pqu: stage A = norm(f); 3 GEMM phases (P, Q, U1a) ----------
__global__ __launch_bounds__(256) void pqu_kernel(
    const float* __restrict__ f, const float* __restrict__ mr,
    const unsigned short* __restrict__ wPT, const unsigned short* __restrict__ wQT,
    const unsigned short* __restrict__ u1aF,
    const float* __restrict__ mW, const float* __restrict__ mb,
    const float* __restrict__ U1, const float* __restrict__ c1,
    const float* __restrict__ u, const float* __restrict__ px,
    const float* __restrict__ py, const float* __restrict__ cp,
    unsigned short* __restrict__ Pn, unsigned short* __restrict__ Qn,
    float* __restrict__ part1)
{
    __shared__ unsigned short lA[4 * 272 * 8];
    __shared__ unsigned short lB[2048 * 8];
    int tid = threadIdx.x;
    int block0 = blockIdx.x * 64;
    int b = block0 >> 14;
    // stage A: normalized f (p-space), bf16 fragments
    {
        int r = tid >> 2, p4 = tid & 3;
        const float4* fsrc = (const float4*)(f + (size_t)(block0 + r) * 128 + p4 * 32);
        const float4* m4 = (const float4*)(mr + b * 256 + p4 * 32);
        const float4* s4 = (const float4*)(mr + b * 256 + 128 + p4 * 32);
#pragma unroll
        for (int j = 0; j < 4; j++) {
            float4 v0 = fsrc[j * 2], v1 = fsrc[j * 2 + 1];
            float4 m0 = m4[j * 2], m1 = m4[j * 2 + 1];
            float4 s0 = s4[j * 2], s1 = s4[j * 2 + 1];
            S8U o;
            o.u[0] = pk2((v0.x - m0.x) * s0.x, (v0.y - m0.y) * s0.y);
            o.u[1] = pk2((v0.z - m0.z) * s0.z, (v0.w - m0.w) * s0.w);
            o.u[2] = pk2((v1.x - m1.x) * s1.x, (v1.y - m1.y) * s1.y);
            o.u[3] = pk2((v1.z - m1.z) * s1.z, (v1.w - m1.w) * s1.w);
            *(short8*)(lA + CHP(r >> 4, p4 * 4 + j, r & 15)) = o.s;
        }
    }
    int w = tid >> 6, lane = tid & 63, lm = lane & 15, lq = lane >> 4;
    float u4[4], px4[4], py4[4];
#pragma unroll
    for (int r = 0; r < 4; r++) {
        int nd = block0 + w * 16 + lq * 4 + r;
        u4[r] = u[nd]; px4[r] = px[nd]; py4[r] = py[nd];
    }
    float cp5[5];
#pragma unroll
    for (int p = 0; p < 5; p++) cp5[p] = cp[b * NP + p];
    float wu[8], wx[8], wy[8], pt[8];

    for (int ph = 0; ph < 3; ph++) {
        const unsigned short* bsrc = (ph == 0) ? wPT : ((ph == 1) ? wQT : u1aF);
        __syncthreads();
#pragma unroll
        for (int i = 0; i < 8; i++)
            *(short8*)(lB + (tid + i * 256) * 8) = *(const short8*)(bsrc + (tid + i * 256) * 8);
        __syncthreads();
        floatx4 acc[8];
#pragma unroll
        for (int t = 0; t < 8; t++) acc[t] = (floatx4)(0.f);
#pragma unroll
        for (int ks = 0; ks < 4; ks++) {
            short8 a = *(const short8*)(lA + CHP(w, ks * 4 + lq, lm));
#pragma unroll
            for (int t = 0; t < 8; t++) {
                short8 bf = *(const short8*)(lB + ((t * 4 + ks) * 64 + lane) * 8);
                acc[t] = __builtin_amdgcn_mfma_f32_16x16x32_bf16(a, bf, acc[t], 0, 0, 0);
            }
        }
        if (ph == 0) {
#pragma unroll
            for (int t = 0; t < 8; t++) {
                int c = t * 16 + lm;
                wu[t] = mW[256 * 128 + c]; wx[t] = mW[257 * 128 + c]; wy[t] = mW[258 * 128 + c];
                float p0 = mb[c];
#pragma unroll
                for (int p = 0; p < 5; p++) p0 += cp5[p] * mW[(259 + p) * 128 + c];
                pt[t] = p0;
            }
#pragma unroll
            for (int r = 0; r < 4; r++) {
                int nd = block0 + w * 16 + lq * 4 + r;
                float v[8];
#pragma unroll
                for (int t = 0; t < 8; t++)
                    v[t] = acc[t][r] + pt[t] + u4[r] * wu[t] + px4[r] * wx[t] + py4[r] * wy[t];
                S8U o;
#pragma unroll
                for (int q = 0; q < 4; q++) o.u[q] = pk2(v[2 * q], v[2 * q + 1]);
                *(short8*)(Pn + (size_t)nd * 128 + lm * 8) = o.s;
            }
        } else if (ph == 1) {
#pragma unroll
            for (int r = 0; r < 4; r++) {
                int nd = block0 + w * 16 + lq * 4 + r;
                float v[8];
#pragma unroll
                for (int t = 0; t < 8; t++)
                    v[t] = acc[t][r] - (u4[r] * wu[t] + px4[r] * wx[t] + py4[r] * wy[t]);
                S8U o;
#pragma unroll
                for (int q = 0; q < 4; q++) o.u[q] = pk2(v[2 * q], v[2 * q + 1]);
                *(short8*)(Qn + (size_t)nd * 128 + lm * 8) = o.s;
            }
        } else {
#pragma unroll
            for (int t = 0; t < 8; t++) {
                int c = t * 16 + lm;
                float p0 = c1[c];
#pragma unroll
                for (int p = 0; p < 5; p++) p0 += cp5[p] * U1[(256 + p) * 128 + c];
                float4 vv;
                vv.x = acc[t][0] + p0; vv.y = acc[t][1] + p0;
                vv.z = acc[t][2] + p0; vv.w = acc[t][3] + p0;
                *(float4*)(part1 + (size_t)blockIdx.x * 8192 + tid * 32 + t * 4) = vv;
            }
        }
    }
}

// ---------- msg: hidden = swish(P[t]+Q[s]); m = swish(hidden@W2+b2); agg ----------
__global__ __launch_bounds__(256) void msg_kernel(
    const unsigned short* __restrict__ Pn, const unsigned short* __restrict__ Qn,
    const unsigned short* __restrict__ w2F, const float* __restrict__ b2,
    unsigned short* __restrict__ aggF)
{
    __shared__ unsigned short lH[4 * 272 * 8];
    __shared__ unsigned short lB[2048 * 8];
    __shared__ unsigned short lAgg[8 * 128];
    int tid = threadIdx.x;
    int base = blockIdx.x * 8;
    int b = base >> 14;
    int a = (base >> 7) & 127;
    int c0 = base & 127;
    // phase 1: 64 hidden rows (8 targets x 8 edges), p-space elementwise
    {
        int row = tid >> 2, p4 = tid & 3;
        int tl = row >> 3, e = row & 7;
        int idx = (e < 4) ? e : e + 1;
        int dx = idx / 3 - 1, dy = idx % 3 - 1;
        int na = a + dx, nc = c0 + tl + dy;
        bool valid = (na >= 0) & (na < 128) & (nc >= 0) & (nc < 128);
        int t = base + tl;
        int s = valid ? ((b << 14) + (na << 7) + nc) : t;
        const unsigned int* Pp = (const unsigned int*)(Pn + (size_t)t * 128 + p4 * 32);
        const unsigned int* Qp = (const unsigned int*)(Qn + (size_t)s * 128 + p4 * 32);
#pragma unroll
        for (int j = 0; j < 4; j++) {
            S8U o;
#pragma unroll
            for (int q = 0; q < 4; q++) {
                unsigned int pu = Pp[j * 4 + q], qu = Qp[j * 4 + q];
                float pl = asf(pu << 16), ph = asf(pu & 0xffff0000u);
                float ql = asf(qu << 16), qh = asf(qu & 0xffff0000u);
                o.u[q] = pk2(swishf(pl + ql), swishf(ph + qh));
            }
            *(short8*)(lH + CHP(row >> 4, p4 * 4 + j, row & 15)) = o.s;
        }
    }
#pragma unroll
    for (int i = 0; i < 8; i++)
        *(short8*)(lB + (tid + i * 256) * 8) = *(const short8*)(w2F + (tid + i * 256) * 8);
    __syncthreads();

    int w = tid >> 6, lane = tid & 63, lm = lane & 15, lq = lane >> 4;
    floatx4 acc[8];
#pragma unroll
    for (int t = 0; t < 8; t++) acc[t] = (floatx4)(0.f);
#pragma unroll
    for (int ks = 0; ks < 4; ks++) {
        short8 af = *(const short8*)(lH + CHP(w, ks * 4 + lq, lm));
#pragma unroll
        for (int t = 0; t < 8; t++) {
            short8 bf = *(const short8*)(lB + ((t * 4 + ks) * 64 + lane) * 8);
            acc[t] = __builtin_amdgcn_mfma_f32_16x16x32_bf16(af, bf, acc[t], 0, 0, 0);
        }
    }
    // epilogue: mask, swish, sum over 8 edges, /deg; pack p-space into lAgg
    float ov[8];
#pragma unroll
    for (int t = 0; t < 8; t++) {
        float bb = b2[t * 16 + lm];
        float s01 = 0.f;
#pragma unroll
        for (int r = 0; r < 4; r++) {
            int row = lq * 4 + r;
            int tl2 = row >> 3;
            int e = row & 7;
            int cc = c0 + w * 2 + tl2;
            int idx = (e < 4) ? e : e + 1;
            int dx = idx / 3 - 1, dy = idx % 3 - 1;
            int na = a + dx, nc = cc + dy;
            bool valid = (na >= 0) & (na < 128) & (nc >= 0) & (nc < 128);
            float m = valid ? swishf(acc[t][r] + bb) : 0.f;
            s01 += m;
        }
        ov[t] = s01 + __shfl_xor(s01, 16);
    }
    if ((lq & 1) == 0) {
        int tl = w * 2 + (lq >> 1);
        int cc = c0 + tl;
        int deg = (1 + (a > 0) + (a < 127)) * (1 + (cc > 0) + (cc < 127)) - 1;
        float inv = 1.f / (float)deg;
        S8U o;
#pragma unroll
        for (int q = 0; q < 4; q++) o.u[q] = pk2(ov[2 * q] * inv, ov[2 * q + 1] * inv);
        *(short8*)(lAgg + tl * 128 + lm * 8) = o.s;
    }
    __syncthreads();
    if (tid < 128) {
        int row8 = tid >> 4, g = tid & 15;
        int n = base + row8;
        size_t lin = (size_t)(n >> 6) * 1024 + (size_t)(((n & 63) >> 4) * 256 + g * 16 + (n & 15));
        *(short8*)(aggF + lin * 8) = *(const short8*)(lAgg + row8 * 128 + g * 8);
    }
}

// ---------- updf: hid = swish(agg@U1b + part1); f = norm(f) + swish(hid@U2 + c2); stats ----
__global__ __launch_bounds__(256) void updf_kernel(
    const unsigned short* __restrict__ aggF, const unsigned short* __restrict__ u1bF,
    const unsigned short* __restrict__ u2F, const float* __restrict__ part1,
    const float* __restrict__ c2, float* __restrict__ f,
    const float* __restrict__ mr, float* __restrict__ stats)
{
    __shared__ unsigned short lAH[4 * 272 * 8];   // agg (linear) then hid (padded)
    __shared__ unsigned short lB[2048 * 8];
    int tid = threadIdx.x;
    int block0 = blockIdx.x * 64;
    int b = block0 >> 14;
#pragma unroll
    for (int i = 0; i < 4; i++) {
        int c = tid + i * 256;
        *(short8*)(lAH + c * 8) = *(const short8*)(aggF + ((size_t)blockIdx.x * 1024 + c) * 8);
    }
#pragma unroll
    for (int i = 0; i < 8; i++)
        *(short8*)(lB + (tid + i * 256) * 8) = *(const short8*)(u1bF + (tid + i * 256) * 8);
    __syncthreads();
    int w = tid >> 6, lane = tid & 63, lm = lane & 15, lq = lane >> 4;
    floatx4 acc[8];
#pragma unroll
    for (int t = 0; t < 8; t++) acc[t] = (floatx4)(0.f);
#pragma unroll
    for (int ks = 0; ks < 4; ks++) {
        short8 a = *(const short8*)(lAH + CHL(w, ks * 4 + lq, lm));
#pragma unroll
        for (int t = 0; t < 8; t++) {
            short8 bf = *(const short8*)(lB + ((t * 4 + ks) * 64 + lane) * 8);
            acc[t] = __builtin_amdgcn_mfma_f32_16x16x32_bf16(a, bf, acc[t], 0, 0, 0);
        }
    }
    __syncthreads();   // done reading lAH (agg) and lB (U1b)
    // epi1: h = swish(acc + part1) -> lHid (padded); reload lB with U2
    float h[8][4];
#pragma unroll
    for (int t = 0; t < 8; t++) {
        float4 pv = *(const float4*)(part1 + (size_t)blockIdx.x * 8192 + tid * 32 + t * 4);
        h[t][0] = swishf(acc[t][0] + pv.x); h[t][1] = swishf(acc[t][1] + pv.y);
        h[t][2] = swishf(acc[t][2] + pv.z); h[t][3] = swishf(acc[t][3] + pv.w);
    }
#pragma unroll
    for (int r = 0; r < 4; r++) {
        S8U o;
#pragma unroll
        for (int q = 0; q < 4; q++) o.u[q] = pk2(h[2 * q][r], h[2 * q + 1][r]);
        *(short8*)(lAH + CHP(w, lm, lq * 4 + r)) = o.s;
    }
#pragma unroll
    for (int i = 0; i < 8; i++)
        *(short8*)(lB + (tid + i * 256) * 8) = *(const short8*)(u2F + (tid + i * 256) * 8);
    __syncthreads();
#pragma unroll
    for (int t = 0; t < 8; t++) acc[t] = (floatx4)(0.f);
#pragma unroll
    for (int ks = 0; ks < 4; ks++) {
        short8 a = *(const short8*)(lAH + CHP(w, ks * 4 + lq, lm));
#pragma unroll
        for (int t = 0; t < 8; t++) {
            short8 bf = *(const short8*)(lB + ((t * 4 + ks) * 64 + lane) * 8);
            acc[t] = __builtin_amdgcn_mfma_f32_16x16x32_bf16(a, bf, acc[t], 0, 0, 0);
        }
    }
    // epi2: fnew = norm(f_old) + swish(acc + c2); write f; stats
    float c2v[8];
#pragma unroll
    for (int t = 0; t < 8; t++) c2v[t] = c2[t * 16 + lm];
    float4 me0 = *(const float4*)(mr + b * 256 + lm * 8);
    float4 me1 = *(const float4*)(mr + b * 256 + lm * 8 + 4);
    float4 rs0 = *(const float4*)(mr + b * 256 + 128 + lm * 8);
    float4 rs1 = *(const float4*)(mr + b * 256 + 128 + lm * 8 + 4);
    float ssum[8], ssq[8];
#pragma unroll
    for (int t = 0; t < 8; t++) { ssum[t] = 0.f; ssq[t] = 0.f; }
#pragma unroll
    for (int r = 0; r < 4; r++) {
        int nd = block0 + w * 16 + lq * 4 + r;
        float4 f0 = *(const float4*)(f + (size_t)nd * 128 + lm * 8);
        float4 f1 = *(const float4*)(f + (size_t)nd * 128 + lm * 8 + 4);
        float fn[8];
        fn[0] = (f0.x - me0.x) * rs0.x + swishf(acc[0][r] + c2v[0]);
        fn[1] = (f0.y - me0.y) * rs0.y + swishf(acc[1][r] + c2v[1]);
        fn[2] = (f0.z - me0.z) * rs0.z + swishf(acc[2][r] + c2v[2]);
        fn[3] = (f0.w - me0.w) * rs0.w + swishf(acc[3][r] + c2v[3]);
        fn[4] = (f1.x - me1.x) * rs1.x + swishf(acc[4][r] + c2v[4]);
        fn[5] = (f1.y - me1.y) * rs1.y + swishf(acc[5][r] + c2v[5]);
        fn[6] = (f1.z - me1.z) * rs1.z + swishf(acc[6][r] + c2v[6]);
        fn[7] = (f1.w - me1.w) * rs1.w + swishf(acc[7][r] + c2v[7]);
        float4 o0 = make_float4(fn[0], fn[1], fn[2], fn[3]);
        float4 o1 = make_float4(fn[4], fn[5], fn[6], fn[7]);
        *(float4*)(f + (size_t)nd * 128 + lm * 8) = o0;
        *(float4*)(f + (size_t)nd * 128 + lm * 8 + 4) = o1;
#pragma unroll
        for (int t = 0; t < 8; t++) { ssum[t] += fn[t]; ssq[t] += fn[t] * fn[t]; }
    }
#pragma unroll
    for (int t = 0; t < 8; t++) {
        float s = ssum[t];
        s += __shfl_xor(s, 16); s += __shfl_xor(s, 32);
        float q = ssq[t];
        q += __shfl_xor(q, 16); q += __shfl_xor(q, 32);
        if (lq == 0) {
            atomicAdd(&stats[b * 256 + lm * 8 + t], s);
            atomicAdd(&stats[b * 256 + 128 + lm * 8 + t], q);
        }
    }
}

// ---------- finalize: stats -> meanrstd (p-space), zero stats ----------
__global__ __launch_bounds__(128) void finalize_kernel(
    float* __restrict__ stats, float* __restrict__ mr)
{
    int b = blockIdx.x, p = threadIdx.x;
    float s = stats[b * 256 + p];
    float s2 = stats[b * 256 + 128 + p];
    float mean = s * (1.f / 16384.f);
    float var = s2 * (1.f / 16384.f) - mean * mean;
    mr[b * 256 + p] = mean;
    mr[b * 256 + 128 + p] = rsqrtf(var + EPS);
    stats[b * 256 + p] = 0.f;
    stats[b * 256 + 128 + p] = 0.f;
}

// ---------- output head: norm(f) @ O1 -> swish -> @ O2; out = u + DT*diff ----------
__global__ __launch_bounds__(256) void out_head(
    const float* __restrict__ f, const float* __restrict__ mr,
    const unsigned short* __restrict__ O1F, const float* __restrict__ ob1,
    const float* __restrict__ O2, const float* __restrict__ ob2,
    const float* __restrict__ u, float* __restrict__ out)
{
    __shared__ unsigned short lA[4 * 272 * 8];
    __shared__ unsigned short lB[1024 * 8];
    int tid = threadIdx.x;
    int block0 = blockIdx.x * 64;
    int b = block0 >> 14;
    {
        int r = tid >> 2, p4 = tid & 3;
        const float4* fsrc = (const float4*)(f + (size_t)(block0 + r) * 128 + p4 * 32);
        const float4* m4 = (const float4*)(mr + b * 256 + p4 * 32);
        const float4* s4 = (const float4*)(mr + b * 256 + 128 + p4 * 32);
#pragma unroll
        for (int j = 0; j < 4; j++) {
            float4 v0 = fsrc[j * 2], v1 = fsrc[j * 2 + 1];
            float4 m0 = m4[j * 2], m1 = m4[j * 2 + 1];
            float4 s0 = s4[j * 2], s1 = s4[j * 2 + 1];
            S8U o;
            o.u[0] = pk2((v0.x - m0.x) * s0.x, (v0.y - m0.y) * s0.y);
            o.u[1] = pk2((v0.z - m0.z) * s0.z, (v0.w - m0.w) * s0.w);
            o.u[2] = pk2((v1.x - m1.x) * s1.x, (v1.y - m1.y) * s1.y);
            o.u[3] = pk2((v1.z - m1.z) * s1.z, (v1.w - m1.w) * s1.w);
            *(short8*)(lA + CHP(r >> 4, p4 * 4 + j, r & 15)) = o.s;
        }
    }
#pragma unroll
    for (int i = 0; i < 4; i++)
        *(short8*)(lB + (tid + i * 256) * 8) = *(const short8*)(O1F + (tid + i * 256) * 8);
    __syncthreads();
    int w = tid >> 6, lane = tid & 63, lm = lane & 15, lq = lane >> 4;
    floatx4 acc[4];
#pragma unroll
    for (int t = 0; t < 4; t++) acc[t] = (floatx4)(0.f);
#pragma unroll
    for (int ks = 0; ks < 4; ks++) {
        short8 a = *(const short8*)(lA + CHP(w, ks * 4 + lq, lm));
#pragma unroll
        for (int t = 0; t < 4; t++) {
            short8 bf = *(const short8*)(lB + ((t * 4 + ks) * 64 + lane) * 8);
            acc[t] = __builtin_amdgcn_mfma_f32_16x16x32_bf16(a, bf, acc[t], 0, 0, 0);
        }
    }
    float b1v[4], o2v[4];
#pragma unroll
    for (int t = 0; t < 4; t++) {
        b1v[t] = ob1[t * 16 + lm];
        o2v[t] = O2[t * 16 + lm];
    }
    float ob2v = ob2[0];
#pragma unroll
    for (int r = 0; r < 4; r++) {
        float s = 0.f;
#pragma unroll
        for (int t = 0; t < 4; t++) s += swishf(acc[t][r] + b1v[t]) * o2v[t];
        s += __shfl_xor(s, 1); s += __shfl_xor(s, 2);
        s += __shfl_xor(s, 4); s += __shfl_xor(s, 8);
        if (lm == 0) {
            int nd = block0 + w * 16 + lq * 4 + r;
            out[nd] = u[nd] + DT * (s + ob2v);
        }
    }
}

extern "C" void kernel_launch(void* const* d_in, const int* in_sizes, int n_in,
                              void* d_out, int out_size, void* d_ws, size_t ws_size,
                              hipStream_t stream)
{
    const float* inputs = (const float*)d_in[0];
    const float* cp     = (const float*)d_in[1];
    const float* emb_W1 = (const float*)d_in[3];
    const float* emb_b1 = (const float*)d_in[4];
    const float* emb_W2 = (const float*)d_in[5];
    const float* emb_b2 = (const float*)d_in[6];
    const float* msg1_W = (const float*)d_in[7];
    const float* msg1_b = (const float*)d_in[8];
    const float* msg2_W = (const float*)d_in[9];
    const float* msg2_b = (const float*)d_in[10];
    const float* upd1_W = (const float*)d_in[11];
    const float* upd1_b = (const float*)d_in[12];
    const float* upd2_W = (const float*)d_in[13];
    const float* upd2_b = (const float*)d_in[14];
    const float* out_W1 = (const float*)d_in[15];
    const float* out_b1 = (const float*)d_in[16];
    const float* out_W2 = (const float*)d_in[17];
    const float* out_b2 = (const float*)d_in[18];
    float* out = (float*)d_out;

    char* base = (char*)d_ws;
    size_t off = 0;
    float* f     = (float*)(base + off); off += (size_t)NNODE * 128 * 4;
    float* part1 = (float*)(base + off); off += (size_t)NNODE * 128 * 4;
    unsigned short* Pn   = (unsigned short*)(base + off); off += (size_t)NNODE * 128 * 2;
    unsigned short* Qn   = (unsigned short*)(base + off); off += (size_t)NNODE * 128 * 2;
    unsigned short* aggF = (unsigned short*)(base + off); off += (size_t)NNODE * 128 * 2;
    float* u    = (float*)(base + off); off += NNODE * 4;
    float* posx = (float*)(base + off); off += NNODE * 4;
    float* posy = (float*)(base + off); off += NNODE * 4;
    float* stats = (float*)(base + off); off += 1024 * 4;
    float* mrbuf = (float*)(base + off); off += 1024 * 4;
    unsigned short* wPT  = (unsigned short*)(base + off); off += 6 * 16384 * 2;
    unsigned short* wQT  = (unsigned short*)(base + off); off += 6 * 16384 * 2;
    unsigned short* w2F  = (unsigned short*)(base + off); off += 6 * 16384 * 2;
    unsigned short* u1aF = (unsigned short*)(base + off); off += 6 * 16384 * 2;
    unsigned short* u1bF = (unsigned short*)(base + off); off += 6 * 16384 * 2;
    unsigned short* u2F  = (unsigned short*)(base + off); off += 6 * 16384 * 2;
    unsigned short* eW2F = (unsigned short*)(base + off); off += 16384 * 2;
    unsigned short* O1F  = (unsigned short*)(base + off); off += 8192 * 2;

    // weight prep
    prep_frag<<<384, 256, 0, stream>>>(msg1_W, wPT, 128, 0,   8, 264 * 128, 1, 6 * 16384);
    prep_frag<<<384, 256, 0, stream>>>(msg1_W, wQT, 128, 128, 8, 264 * 128, 1, 6 * 16384);
    prep_frag<<<384, 256, 0, stream>>>(msg2_W, w2F, 128, 0,   8, 128 * 128, 1, 6 * 16384);
    prep_frag<<<384, 256, 0, stream>>>(upd1_W, u1aF, 128, 0,   8, 261 * 128, 1, 6 * 16384);
    prep_frag<<<384, 256, 0, stream>>>(upd1_W, u1bF, 128, 128, 8, 261 * 128, 1, 6 * 16384);
    prep_frag<<<384, 256, 0, stream>>>(upd2_W, u2F, 128, 0,   8, 128 * 128, 1, 6 * 16384);
    prep_frag<<<64, 256, 0, stream>>>(emb_W2, eW2F, 128, 0,   8, 0, 0, 16384);
    prep_frag<<<32, 256, 0, stream>>>(out_W1, O1F, 64, 0,    4, 0, 1, 8192);

    node_init<<<256, 256, 0, stream>>>(inputs, cp, u, posx, posy, stats, mrbuf);
    embed_mfma<<<1024, 256, 0, stream>>>(u, posx, posy, cp, emb_W1, emb_b1, eW2F, emb_b2, f);
    for (int l = 0; l < 6; l++) {
        pqu_kernel<<<1024, 256, 0, stream>>>(f, mrbuf,
            wPT + (size_t)l * 16384, wQT + (size_t)l * 16384, u1aF + (size_t)l * 16384,
            msg1_W + (size_t)l * 264 * 128, msg1_b + (size_t)l * 128,
            upd1_W + (size_t)l * 261 * 128, upd1_b + (size_t)l * 128,
            u, posx, posy, cp, Pn, Qn, part1);
        msg_kernel<<<8192, 256, 0, stream>>>(Pn, Qn,
            w2F + (size_t)l * 16384, msg2_b + (size_t)l * 128, aggF);
        updf_kernel<<<1024, 256, 0, stream>>>(aggF,
            u1bF + (size_t)l * 16384, u2F + (size_t)l * 16384, part1,
            upd2_b + (size_t)l * 128, f, mrbuf, stats);
        finalize_kernel<<<4, 128, 0, stream>>>(stats, mrbuf);
    }
    out_head<<<1024, 256, 0, stream>>>(f, mrbuf, O1F, out_b1, out_W2, out_b2, u, out);
}

// Round 4
// 1152.163 us; speedup vs baseline: 2.9335x; 2.9335x over previous
//
#include <hip/hip_runtime.h>
#include <hip/hip_bf16.h>
#include <math.h>

#define NNODE 65536
#define NBAT  16384
#define NP    5
#define DT    0.1f
#define EPS   1e-5f

typedef __attribute__((ext_vector_type(8))) short short8;
typedef __attribute__((ext_vector_type(4))) float floatx4;

union S8U { short8 s; unsigned int u[4]; };

__device__ __forceinline__ float swishf(float x) {
    return x / (1.f + __expf(-x));
}
__device__ __forceinline__ float asf(unsigned int u) {
    union { unsigned int u; float f; } x; x.u = u; return x.f;
}
__device__ __forceinline__ unsigned short f2b(float f) {
    union { float f; unsigned int u; } x; x.f = f;
    unsigned int r = x.u + 0x7fff + ((x.u >> 16) & 1);
    return (unsigned short)(r >> 16);
}
__device__ __forceinline__ unsigned int pk2(float a, float b) {
    __hip_bfloat162 h = __float22bfloat162_rn(make_float2(a, b));
    union { __hip_bfloat162 h; unsigned int u; } x; x.h = h; return x.u;
}

// padded fragment chunk offset (in shorts)
#define CHP(w, g, r15) ((((w) * 272) + (g) * 17 + (r15)) * 8)
// linear fragment chunk offset (in shorts)
#define CHL(w, g, r15) ((((w) * 256) + (g) * 16 + (r15)) * 8)

// ---------- weight prep: fp32 [L][rows][ldn] -> bf16 fragment-linear ----------
__global__ __launch_bounds__(256) void prep_frag(
    const float* __restrict__ src, unsigned short* __restrict__ dst,
    int ldn, int koff, int NT, int lstride, int perm, int total)
{
    int i = blockIdx.x * 256 + threadIdx.x;
    if (i >= total) return;
    int nper = NT << 11;
    int l = i / nper;
    int r0 = i - l * nper;
    int t = r0 >> 11;
    int ks = (r0 >> 9) & 3;
    int lane = (r0 >> 3) & 63;
    int j = r0 & 7;
    int lm = lane & 15, lq = lane >> 4;
    int p = ks * 32 + lq * 8 + j;
    int k = perm ? ((p & 7) * 16 + (p >> 3)) : p;
    int n = t * 16 + lm;
    dst[i] = f2b(src[(size_t)l * lstride + (size_t)(koff + k) * ldn + n]);
}

// ---------- node scalars + meanrstd identity init ----------
__global__ __launch_bounds__(256) void node_init(
    const float* __restrict__ inp, const float* __restrict__ cp,
    float* __restrict__ u, float* __restrict__ posx, float* __restrict__ posy,
    float* __restrict__ mr)
{
    int n = blockIdx.x * 256 + threadIdx.x;
    int b = n >> 14, r = n & 16383;
    int a = r >> 7, c = r & 127;
    u[n] = inp[b * 3 * NBAT + r];
    posx[n] = (a * (1.f / 127.f)) * cp[b * NP + 1];
    posy[n] = (c * (1.f / 127.f)) * cp[b * NP + 0];
    if (n < 1024) mr[n] = ((n >> 7) & 1) ? 1.f : 0.f;   // mean 0, rstd 1
}

// ---------- embedding: 8 -> 128 (VALU) -> 128 (MFMA); f written p-space fp32 ----------
__global__ __launch_bounds__(256) void embed_mfma(
    const float* __restrict__ u, const float* __restrict__ posx,
    const float* __restrict__ posy, const float* __restrict__ cp,
    const float* __restrict__ W1, const float* __restrict__ b1,
    const unsigned short* __restrict__ W2F, const float* __restrict__ b2,
    float* __restrict__ f)
{
    __shared__ unsigned short lA[4 * 272 * 8];
    __shared__ unsigned short lB[2048 * 8];
    int tid = threadIdx.x;
    int block0 = blockIdx.x * 64;
    {
        int r = tid >> 2, p4 = tid & 3;
        int n = block0 + r;
        int b = n >> 14;
        float e8[8];
        e8[0] = u[n]; e8[1] = posx[n]; e8[2] = posy[n];
#pragma unroll
        for (int p = 0; p < 5; p++) e8[3 + p] = cp[b * NP + p];
        float a32[32];
        const float4* b4 = (const float4*)(b1 + p4 * 32);
#pragma unroll
        for (int q = 0; q < 8; q++) {
            float4 bv = b4[q];
            a32[q * 4 + 0] = bv.x; a32[q * 4 + 1] = bv.y;
            a32[q * 4 + 2] = bv.z; a32[q * 4 + 3] = bv.w;
        }
#pragma unroll
        for (int i = 0; i < 8; i++) {
            const float4* w4 = (const float4*)(W1 + i * 128 + p4 * 32);
            float ev = e8[i];
#pragma unroll
            for (int q = 0; q < 8; q++) {
                float4 wv = w4[q];
                a32[q * 4 + 0] += ev * wv.x; a32[q * 4 + 1] += ev * wv.y;
                a32[q * 4 + 2] += ev * wv.z; a32[q * 4 + 3] += ev * wv.w;
            }
        }
#pragma unroll
        for (int j = 0; j < 4; j++) {
            S8U o;
#pragma unroll
            for (int q = 0; q < 4; q++)
                o.u[q] = pk2(swishf(a32[j * 8 + 2 * q]), swishf(a32[j * 8 + 2 * q + 1]));
            *(short8*)(lA + CHP(r >> 4, p4 * 4 + j, r & 15)) = o.s;
        }
    }
#pragma unroll
    for (int i = 0; i < 8; i++)
        *(short8*)(lB + (tid + i * 256) * 8) = *(const short8*)(W2F + (tid + i * 256) * 8);
    __syncthreads();
    int w = tid >> 6, lane = tid & 63, lm = lane & 15, lq = lane >> 4;
    floatx4 acc[8];
#pragma unroll
    for (int t = 0; t < 8; t++) acc[t] = (floatx4)(0.f);
#pragma unroll
    for (int ks = 0; ks < 4; ks++) {
        short8 a = *(const short8*)(lA + CHP(w, ks * 4 + lq, lm));
#pragma unroll
        for (int t = 0; t < 8; t++) {
            short8 bf = *(const short8*)(lB + ((t * 4 + ks) * 64 + lane) * 8);
            acc[t] = __builtin_amdgcn_mfma_f32_16x16x32_bf16(a, bf, acc[t], 0, 0, 0);
        }
    }
    float bias2[8];
#pragma unroll
    for (int t = 0; t < 8; t++) bias2[t] = b2[t * 16 + lm];
#pragma unroll
    for (int r = 0; r < 4; r++) {
        int nd = block0 + w * 16 + lq * 4 + r;
        float4 v0, v1;
        v0.x = swishf(acc[0][r] + bias2[0]); v0.y = swishf(acc[1][r] + bias2[1]);
        v0.z = swishf(acc[2][r] + bias2[2]); v0.w = swishf(acc[3][r] + bias2[3]);
        v1.x = swishf(acc[4][r] + bias2[4]); v1.y = swishf(acc[5][r] + bias2[5]);
        v1.z = swishf(acc[6][r] + bias2[6]); v1.w = swishf(acc[7][r] + bias2[7]);
        *(float4*)(f + (size_t)nd * 128 + lm * 8) = v0;
        *(float4*)(f + (size_t)nd * 128 + lm * 8 + 4) = v1;
    }
}

// ---------- pqu: stage A = norm(f); 2 GEMM phases (P, Q) ----------
__global__ __launch_bounds__(256) void pqu_kernel(
    const float* __restrict__ f, const float* __restrict__ mr,
    const unsigned short* __restrict__ wPT, const unsigned short* __restrict__ wQT,
    const float* __restrict__ mW, const float* __restrict__ mb,
    const float* __restrict__ u, const float* __restrict__ px,
    const float* __restrict__ py, const float* __restrict__ cp,
    unsigned short* __restrict__ Pn, unsigned short* __restrict__ Qn)
{
    __shared__ unsigned short lA[4 * 272 * 8];
    __shared__ unsigned short lB[2048 * 8];
    int tid = threadIdx.x;
    int block0 = blockIdx.x * 64;
    int b = block0 >> 14;
    {
        int r = tid >> 2, p4 = tid & 3;
        const float4* fsrc = (const float4*)(f + (size_t)(block0 + r) * 128 + p4 * 32);
        const float4* m4 = (const float4*)(mr + b * 256 + p4 * 32);
        const float4* s4 = (const float4*)(mr + b * 256 + 128 + p4 * 32);
#pragma unroll
        for (int j = 0; j < 4; j++) {
            float4 v0 = fsrc[j * 2], v1 = fsrc[j * 2 + 1];
            float4 m0 = m4[j * 2], m1 = m4[j * 2 + 1];
            float4 s0 = s4[j * 2], s1 = s4[j * 2 + 1];
            S8U o;
            o.u[0] = pk2((v0.x - m0.x) * s0.x, (v0.y - m0.y) * s0.y);
            o.u[1] = pk2((v0.z - m0.z) * s0.z, (v0.w - m0.w) * s0.w);
            o.u[2] = pk2((v1.x - m1.x) * s1.x, (v1.y - m1.y) * s1.y);
            o.u[3] = pk2((v1.z - m1.z) * s1.z, (v1.w - m1.w) * s1.w);
            *(short8*)(lA + CHP(r >> 4, p4 * 4 + j, r & 15)) = o.s;
        }
    }
    int w = tid >> 6, lane = tid & 63, lm = lane & 15, lq = lane >> 4;
    float u4[4], px4[4], py4[4];
#pragma unroll
    for (int r = 0; r < 4; r++) {
        int nd = block0 + w * 16 + lq * 4 + r;
        u4[r] = u[nd]; px4[r] = px[nd]; py4[r] = py[nd];
    }
    float cp5[5];
#pragma unroll
    for (int p = 0; p < 5; p++) cp5[p] = cp[b * NP + p];
    float wu[8], wx[8], wy[8], pt[8];

    for (int ph = 0; ph < 2; ph++) {
        const unsigned short* bsrc = (ph == 0) ? wPT : wQT;
        __syncthreads();
#pragma unroll
        for (int i = 0; i < 8; i++)
            *(short8*)(lB + (tid + i * 256) * 8) = *(const short8*)(bsrc + (tid + i * 256) * 8);
        __syncthreads();
        floatx4 acc[8];
#pragma unroll
        for (int t = 0; t < 8; t++) acc[t] = (floatx4)(0.f);
#pragma unroll
        for (int ks = 0; ks < 4; ks++) {
            short8 a = *(const short8*)(lA + CHP(w, ks * 4 + lq, lm));
#pragma unroll
            for (int t = 0; t < 8; t++) {
                short8 bf = *(const short8*)(lB + ((t * 4 + ks) * 64 + lane) * 8);
                acc[t] = __builtin_amdgcn_mfma_f32_16x16x32_bf16(a, bf, acc[t], 0, 0, 0);
            }
        }
        if (ph == 0) {
#pragma unroll
            for (int t = 0; t < 8; t++) {
                int c = t * 16 + lm;
                wu[t] = mW[256 * 128 + c]; wx[t] = mW[257 * 128 + c]; wy[t] = mW[258 * 128 + c];
                float p0 = mb[c];
#pragma unroll
                for (int p = 0; p < 5; p++) p0 += cp5[p] * mW[(259 + p) * 128 + c];
                pt[t] = p0;
            }
#pragma unroll
            for (int r = 0; r < 4; r++) {
                int nd = block0 + w * 16 + lq * 4 + r;
                float v[8];
#pragma unroll
                for (int t = 0; t < 8; t++)
                    v[t] = acc[t][r] + pt[t] + u4[r] * wu[t] + px4[r] * wx[t] + py4[r] * wy[t];
                S8U o;
#pragma unroll
                for (int q = 0; q < 4; q++) o.u[q] = pk2(v[2 * q], v[2 * q + 1]);
                *(short8*)(Pn + (size_t)nd * 128 + lm * 8) = o.s;
            }
        } else {
#pragma unroll
            for (int r = 0; r < 4; r++) {
                int nd = block0 + w * 16 + lq * 4 + r;
                float v[8];
#pragma unroll
                for (int t = 0; t < 8; t++)
                    v[t] = acc[t][r] - (u4[r] * wu[t] + px4[r] * wx[t] + py4[r] * wy[t]);
                S8U o;
#pragma unroll
                for (int q = 0; q < 4; q++) o.u[q] = pk2(v[2 * q], v[2 * q + 1]);
                *(short8*)(Qn + (size_t)nd * 128 + lm * 8) = o.s;
            }
        }
    }
}

// ---------- msg: hidden = swish(P[t]+Q[s]); m = swish(hidden@W2+b2); agg ----------
__global__ __launch_bounds__(256) void msg_kernel(
    const unsigned short* __restrict__ Pn, const unsigned short* __restrict__ Qn,
    const unsigned short* __restrict__ w2F, const float* __restrict__ b2,
    unsigned short* __restrict__ aggF)
{
    __shared__ unsigned short lH[4 * 272 * 8];
    __shared__ unsigned short lB[2048 * 8];
    __shared__ unsigned short lAgg[8 * 128];
    int tid = threadIdx.x;
    int base = blockIdx.x * 8;
    int b = base >> 14;
    int a = (base >> 7) & 127;
    int c0 = base & 127;
    {
        int row = tid >> 2, p4 = tid & 3;
        int tl = row >> 3, e = row & 7;
        int idx = (e < 4) ? e : e + 1;
        int dx = idx / 3 - 1, dy = idx % 3 - 1;
        int na = a + dx, nc = c0 + tl + dy;
        bool valid = (na >= 0) & (na < 128) & (nc >= 0) & (nc < 128);
        int t = base + tl;
        int s = valid ? ((b << 14) + (na << 7) + nc) : t;
        const unsigned int* Pp = (const unsigned int*)(Pn + (size_t)t * 128 + p4 * 32);
        const unsigned int* Qp = (const unsigned int*)(Qn + (size_t)s * 128 + p4 * 32);
#pragma unroll
        for (int j = 0; j < 4; j++) {
            S8U o;
#pragma unroll
            for (int q = 0; q < 4; q++) {
                unsigned int pu = Pp[j * 4 + q], qu = Qp[j * 4 + q];
                float pl = asf(pu << 16), ph = asf(pu & 0xffff0000u);
                float ql = asf(qu << 16), qh = asf(qu & 0xffff0000u);
                o.u[q] = pk2(swishf(pl + ql), swishf(ph + qh));
            }
            *(short8*)(lH + CHP(row >> 4, p4 * 4 + j, row & 15)) = o.s;
        }
    }
#pragma unroll
    for (int i = 0; i < 8; i++)
        *(short8*)(lB + (tid + i * 256) * 8) = *(const short8*)(w2F + (tid + i * 256) * 8);
    __syncthreads();

    int w = tid >> 6, lane = tid & 63, lm = lane & 15, lq = lane >> 4;
    floatx4 acc[8];
#pragma unroll
    for (int t = 0; t < 8; t++) acc[t] = (floatx4)(0.f);
#pragma unroll
    for (int ks = 0; ks < 4; ks++) {
        short8 af = *(const short8*)(lH + CHP(w, ks * 4 + lq, lm));
#pragma unroll
        for (int t = 0; t < 8; t++) {
            short8 bf = *(const short8*)(lB + ((t * 4 + ks) * 64 + lane) * 8);
            acc[t] = __builtin_amdgcn_mfma_f32_16x16x32_bf16(af, bf, acc[t], 0, 0, 0);
        }
    }
    float ov[8];
#pragma unroll
    for (int t = 0; t < 8; t++) {
        float bb = b2[t * 16 + lm];
        float s01 = 0.f;
#pragma unroll
        for (int r = 0; r < 4; r++) {
            int row = lq * 4 + r;
            int tl2 = row >> 3;
            int e = row & 7;
            int cc = c0 + w * 2 + tl2;
            int idx = (e < 4) ? e : e + 1;
            int dx = idx / 3 - 1, dy = idx % 3 - 1;
            int na = a + dx, nc = cc + dy;
            bool valid = (na >= 0) & (na < 128) & (nc >= 0) & (nc < 128);
            float m = valid ? swishf(acc[t][r] + bb) : 0.f;
            s01 += m;
        }
        ov[t] = s01 + __shfl_xor(s01, 16);
    }
    if ((lq & 1) == 0) {
        int tl = w * 2 + (lq >> 1);
        int cc = c0 + tl;
        int deg = (1 + (a > 0) + (a < 127)) * (1 + (cc > 0) + (cc < 127)) - 1;
        float inv = 1.f / (float)deg;
        S8U o;
#pragma unroll
        for (int q = 0; q < 4; q++) o.u[q] = pk2(ov[2 * q] * inv, ov[2 * q + 1] * inv);
        *(short8*)(lAgg + tl * 128 + lm * 8) = o.s;
    }
    __syncthreads();
    if (tid < 128) {
        int row8 = tid >> 4, g = tid & 15;
        int n = base + row8;
        size_t lin = (size_t)(n >> 6) * 1024 + (size_t)(((n & 63) >> 4) * 256 + g * 16 + (n & 15));
        *(short8*)(aggF + lin * 8) = *(const short8*)(lAgg + row8 * 128 + g * 8);
    }
}

// ---------- updf: hid = swish(normf@U1a + agg@U1b + bias); f = norm(f) + swish(hid@U2 + c2);
//            per-block partial stats (NO atomics) ----------
__global__ __launch_bounds__(256) void updf_kernel(
    float* __restrict__ f, const float* __restrict__ mr,
    const unsigned short* __restrict__ aggF,
    const unsigned short* __restrict__ u1aF, const unsigned short* __restrict__ u1bF,
    const unsigned short* __restrict__ u2F,
    const float* __restrict__ U1, const float* __restrict__ c1,
    const float* __restrict__ c2, const float* __restrict__ cp,
    float* __restrict__ partials)
{
    __shared__ unsigned short lA[4 * 272 * 8];
    __shared__ unsigned short lB[2048 * 8];
    int tid = threadIdx.x;
    int block0 = blockIdx.x * 64;
    int b = block0 >> 14;
    int w = tid >> 6, lane = tid & 63, lm = lane & 15, lq = lane >> 4;

    // phase 1: stage normf (padded) + U1a; GEMM
    {
        int r = tid >> 2, p4 = tid & 3;
        const float4* fsrc = (const float4*)(f + (size_t)(block0 + r) * 128 + p4 * 32);
        const float4* m4 = (const float4*)(mr + b * 256 + p4 * 32);
        const float4* s4 = (const float4*)(mr + b * 256 + 128 + p4 * 32);
#pragma unroll
        for (int j = 0; j < 4; j++) {
            float4 v0 = fsrc[j * 2], v1 = fsrc[j * 2 + 1];
            float4 m0 = m4[j * 2], m1 = m4[j * 2 + 1];
            float4 s0 = s4[j * 2], s1 = s4[j * 2 + 1];
            S8U o;
            o.u[0] = pk2((v0.x - m0.x) * s0.x, (v0.y - m0.y) * s0.y);
            o.u[1] = pk2((v0.z - m0.z) * s0.z, (v0.w - m0.w) * s0.w);
            o.u[2] = pk2((v1.x - m1.x) * s1.x, (v1.y - m1.y) * s1.y);
            o.u[3] = pk2((v1.z - m1.z) * s1.z, (v1.w - m1.w) * s1.w);
            *(short8*)(lA + CHP(r >> 4, p4 * 4 + j, r & 15)) = o.s;
        }
    }
#pragma unroll
    for (int i = 0; i < 8; i++)
        *(short8*)(lB + (tid + i * 256) * 8) = *(const short8*)(u1aF + (tid + i * 256) * 8);
    __syncthreads();
    floatx4 acc[8];
#pragma unroll
    for (int t = 0; t < 8; t++) acc[t] = (floatx4)(0.f);
#pragma unroll
    for (int ks = 0; ks < 4; ks++) {
        short8 a = *(const short8*)(lA + CHP(w, ks * 4 + lq, lm));
#pragma unroll
        for (int t = 0; t < 8; t++) {
            short8 bf = *(const short8*)(lB + ((t * 4 + ks) * 64 + lane) * 8);
            acc[t] = __builtin_amdgcn_mfma_f32_16x16x32_bf16(a, bf, acc[t], 0, 0, 0);
        }
    }
    __syncthreads();

    // phase 2: stage agg (linear) + U1b; GEMM accumulate
#pragma unroll
    for (int i = 0; i < 4; i++)
        *(short8*)(lA + (tid + i * 256) * 8) =
            *(const short8*)(aggF + ((size_t)blockIdx.x * 1024 + tid + i * 256) * 8);
#pragma unroll
    for (int i = 0; i < 8; i++)
        *(short8*)(lB + (tid + i * 256) * 8) = *(const short8*)(u1bF + (tid + i * 256) * 8);
    __syncthreads();
#pragma unroll
    for (int ks = 0; ks < 4; ks++) {
        short8 a = *(const short8*)(lA + CHL(w, ks * 4 + lq, lm));
#pragma unroll
        for (int t = 0; t < 8; t++) {
            short8 bf = *(const short8*)(lB + ((t * 4 + ks) * 64 + lane) * 8);
            acc[t] = __builtin_amdgcn_mfma_f32_16x16x32_bf16(a, bf, acc[t], 0, 0, 0);
        }
    }
    __syncthreads();

    // epi1: h = swish(acc + bias); write h fragments; stage U2
    float cp5[5];
#pragma unroll
    for (int p = 0; p < 5; p++) cp5[p] = cp[b * NP + p];
    float pt[8];
#pragma unroll
    for (int t = 0; t < 8; t++) {
        int c = t * 16 + lm;
        float p0 = c1[c];
#pragma unroll
        for (int p = 0; p < 5; p++) p0 += cp5[p] * U1[(256 + p) * 128 + c];
        pt[t] = p0;
    }
#pragma unroll
    for (int r = 0; r < 4; r++) {
        S8U o;
#pragma unroll
        for (int q = 0; q < 4; q++)
            o.u[q] = pk2(swishf(acc[2 * q][r] + pt[2 * q]),
                         swishf(acc[2 * q + 1][r] + pt[2 * q + 1]));
        *(short8*)(lA + CHP(w, lm, lq * 4 + r)) = o.s;
    }
#pragma unroll
    for (int i = 0; i < 8; i++)
        *(short8*)(lB + (tid + i * 256) * 8) = *(const short8*)(u2F + (tid + i * 256) * 8);
    __syncthreads();

    // phase 3: GEMM hid @ U2
#pragma unroll
    for (int t = 0; t < 8; t++) acc[t] = (floatx4)(0.f);
#pragma unroll
    for (int ks = 0; ks < 4; ks++) {
        short8 a = *(const short8*)(lA + CHP(w, ks * 4 + lq, lm));
#pragma unroll
        for (int t = 0; t < 8; t++) {
            short8 bf = *(const short8*)(lB + ((t * 4 + ks) * 64 + lane) * 8);
            acc[t] = __builtin_amdgcn_mfma_f32_16x16x32_bf16(a, bf, acc[t], 0, 0, 0);
        }
    }

    // epi2: fn = norm(f_old) + swish(acc + c2); write f; partial stats
    float c2v[8];
#pragma unroll
    for (int t = 0; t < 8; t++) c2v[t] = c2[t * 16 + lm];
    float4 me0 = *(const float4*)(mr + b * 256 + lm * 8);
    float4 me1 = *(const float4*)(mr + b * 256 + lm * 8 + 4);
    float4 rs0 = *(const float4*)(mr + b * 256 + 128 + lm * 8);
    float4 rs1 = *(const float4*)(mr + b * 256 + 128 + lm * 8 + 4);
    float ssum[8], ssq[8];
#pragma unroll
    for (int t = 0; t < 8; t++) { ssum[t] = 0.f; ssq[t] = 0.f; }
#pragma unroll
    for (int r = 0; r < 4; r++) {
        int nd = block0 + w * 16 + lq * 4 + r;
        float4 f0 = *(const float4*)(f + (size_t)nd * 128 + lm * 8);
        float4 f1 = *(const float4*)(f + (size_t)nd * 128 + lm * 8 + 4);
        float fn[8];
        fn[0] = (f0.x - me0.x) * rs0.x + swishf(acc[0][r] + c2v[0]);
        fn[1] = (f0.y - me0.y) * rs0.y + swishf(acc[1][r] + c2v[1]);
        fn[2] = (f0.z - me0.z) * rs0.z + swishf(acc[2][r] + c2v[2]);
        fn[3] = (f0.w - me0.w) * rs0.w + swishf(acc[3][r] + c2v[3]);
        fn[4] = (f1.x - me1.x) * rs1.x + swishf(acc[4][r] + c2v[4]);
        fn[5] = (f1.y - me1.y) * rs1.y + swishf(acc[5][r] + c2v[5]);
        fn[6] = (f1.z - me1.z) * rs1.z + swishf(acc[6][r] + c2v[6]);
        fn[7] = (f1.w - me1.w) * rs1.w + swishf(acc[7][r] + c2v[7]);
        *(float4*)(f + (size_t)nd * 128 + lm * 8) = make_float4(fn[0], fn[1], fn[2], fn[3]);
        *(float4*)(f + (size_t)nd * 128 + lm * 8 + 4) = make_float4(fn[4], fn[5], fn[6], fn[7]);
#pragma unroll
        for (int t = 0; t < 8; t++) { ssum[t] += fn[t]; ssq[t] += fn[t] * fn[t]; }
    }
    // reduce across lq within wave
#pragma unroll
    for (int t = 0; t < 8; t++) {
        ssum[t] += __shfl_xor(ssum[t], 16); ssum[t] += __shfl_xor(ssum[t], 32);
        ssq[t]  += __shfl_xor(ssq[t], 16);  ssq[t]  += __shfl_xor(ssq[t], 32);
    }
    __syncthreads();                 // all waves done with lB
    float* red = (float*)lB;         // 4 * 256 floats
    if (lq == 0) {
#pragma unroll
        for (int t = 0; t < 8; t++) {
            red[w * 256 + lm * 8 + t] = ssum[t];
            red[w * 256 + 128 + lm * 8 + t] = ssq[t];
        }
    }
    __syncthreads();
    {
        float v = red[tid] + red[256 + tid] + red[512 + tid] + red[768 + tid];
        partials[(size_t)blockIdx.x * 256 + tid] = v;
    }
}

// ---------- finalize: reduce 256 partials per batch -> meanrstd ----------
__global__ __launch_bounds__(256) void finalize_kernel(
    const float* __restrict__ partials, float* __restrict__ mr)
{
    __shared__ float s[256];
    int b = blockIdx.x, tid = threadIdx.x;
    float acc = 0.f;
    const float* p = partials + (size_t)b * 256 * 256 + tid;
#pragma unroll 8
    for (int i = 0; i < 256; i++) acc += p[i * 256];
    s[tid] = acc;
    __syncthreads();
    if (tid < 128) {
        float mean = s[tid] * (1.f / 16384.f);
        float var = s[128 + tid] * (1.f / 16384.f) - mean * mean;
        mr[b * 256 + tid] = mean;
        mr[b * 256 + 128 + tid] = rsqrtf(var + EPS);
    }
}

// ---------- output head ----------
__global__ __launch_bounds__(256) void out_head(
    const float* __restrict__ f, const float* __restrict__ mr,
    const unsigned short* __restrict__ O1F, const float* __restrict__ ob1,
    const float* __restrict__ O2, const float* __restrict__ ob2,
    const float* __restrict__ u, float* __restrict__ out)
{
    __shared__ unsigned short lA[4 * 272 * 8];
    __shared__ unsigned short lB[1024 * 8];
    int tid = threadIdx.x;
    int block0 = blockIdx.x * 64;
    int b = block0 >> 14;
    {
        int r = tid >> 2, p4 = tid & 3;
        const float4* fsrc = (const float4*)(f + (size_t)(block0 + r) * 128 + p4 * 32);
        const float4* m4 = (const float4*)(mr + b * 256 + p4 * 32);
        const float4* s4 = (const float4*)(mr + b * 256 + 128 + p4 * 32);
#pragma unroll
        for (int j = 0; j < 4; j++) {
            float4 v0 = fsrc[j * 2], v1 = fsrc[j * 2 + 1];
            float4 m0 = m4[j * 2], m1 = m4[j * 2 + 1];
            float4 s0 = s4[j * 2], s1 = s4[j * 2 + 1];
            S8U o;
            o.u[0] = pk2((v0.x - m0.x) * s0.x, (v0.y - m0.y) * s0.y);
            o.u[1] = pk2((v0.z - m0.z) * s0.z, (v0.w - m0.w) * s0.w);
            o.u[2] = pk2((v1.x - m1.x) * s1.x, (v1.y - m1.y) * s1.y);
            o.u[3] = pk2((v1.z - m1.z) * s1.z, (v1.w - m1.w) * s1.w);
            *(short8*)(lA + CHP(r >> 4, p4 * 4 + j, r & 15)) = o.s;
        }
    }
#pragma unroll
    for (int i = 0; i < 4; i++)
        *(short8*)(lB + (tid + i * 256) * 8) = *(const short8*)(O1F + (tid + i * 256) * 8);
    __syncthreads();
    int w = tid >> 6, lane = tid & 63, lm = lane & 15, lq = lane >> 4;
    floatx4 acc[4];
#pragma unroll
    for (int t = 0; t < 4; t++) acc[t] = (floatx4)(0.f);
#pragma unroll
    for (int ks = 0; ks < 4; ks++) {
        short8 a = *(const short8*)(lA + CHP(w, ks * 4 + lq, lm));
#pragma unroll
        for (int t = 0; t < 4; t++) {
            short8 bf = *(const short8*)(lB + ((t * 4 + ks) * 64 + lane) * 8);
            acc[t] = __builtin_amdgcn_mfma_f32_16x16x32_bf16(a, bf, acc[t], 0, 0, 0);
        }
    }
    float b1v[4], o2v[4];
#pragma unroll
    for (int t = 0; t < 4; t++) {
        b1v[t] = ob1[t * 16 + lm];
        o2v[t] = O2[t * 16 + lm];
    }
    float ob2v = ob2[0];
#pragma unroll
    for (int r = 0; r < 4; r++) {
        float s = 0.f;
#pragma unroll
        for (int t = 0; t < 4; t++) s += swishf(acc[t][r] + b1v[t]) * o2v[t];
        s += __shfl_xor(s, 1); s += __shfl_xor(s, 2);
        s += __shfl_xor(s, 4); s += __shfl_xor(s, 8);
        if (lm == 0) {
            int nd = block0 + w * 16 + lq * 4 + r;
            out[nd] = u[nd] + DT * (s + ob2v);
        }
    }
}

extern "C" void kernel_launch(void* const* d_in, const int* in_sizes, int n_in,
                              void* d_out, int out_size, void* d_ws, size_t ws_size,
                              hipStream_t stream)
{
    const float* inputs = (const float*)d_in[0];
    const float* cp     = (const float*)d_in[1];
    const float* emb_W1 = (const float*)d_in[3];
    const float* emb_b1 = (const float*)d_in[4];
    const float* emb_W2 = (const float*)d_in[5];
    const float* emb_b2 = (const float*)d_in[6];
    const float* msg1_W = (const float*)d_in[7];
    const float* msg1_b = (const float*)d_in[8];
    const float* msg2_W = (const float*)d_in[9];
    const float* msg2_b = (const float*)d_in[10];
    const float* upd1_W = (const float*)d_in[11];
    const float* upd1_b = (const float*)d_in[12];
    const float* upd2_W = (const float*)d_in[13];
    const float* upd2_b = (const float*)d_in[14];
    const float* out_W1 = (const float*)d_in[15];
    const float* out_b1 = (const float*)d_in[16];
    const float* out_W2 = (const float*)d_in[17];
    const float* out_b2 = (const float*)d_in[18];
    float* out = (float*)d_out;

    char* base = (char*)d_ws;
    size_t off = 0;
    float* f     = (float*)(base + off); off += (size_t)NNODE * 128 * 4;
    unsigned short* Pn   = (unsigned short*)(base + off); off += (size_t)NNODE * 128 * 2;
    unsigned short* Qn   = (unsigned short*)(base + off); off += (size_t)NNODE * 128 * 2;
    unsigned short* aggF = (unsigned short*)(base + off); off += (size_t)NNODE * 128 * 2;
    float* u    = (float*)(base + off); off += NNODE * 4;
    float* posx = (float*)(base + off); off += NNODE * 4;
    float* posy = (float*)(base + off); off += NNODE * 4;
    float* partials = (float*)(base + off); off += 1024 * 256 * 4;
    float* mrbuf = (float*)(base + off); off += 1024 * 4;
    unsigned short* wPT  = (unsigned short*)(base + off); off += 6 * 16384 * 2;
    unsigned short* wQT  = (unsigned short*)(base + off); off += 6 * 16384 * 2;
    unsigned short* w2F  = (unsigned short*)(base + off); off += 6 * 16384 * 2;
    unsigned short* u1aF = (unsigned short*)(base + off); off += 6 * 16384 * 2;
    unsigned short* u1bF = (unsigned short*)(base + off); off += 6 * 16384 * 2;
    unsigned short* u2F  = (unsigned short*)(base + off); off += 6 * 16384 * 2;
    unsigned short* eW2F = (unsigned short*)(base + off); off += 16384 * 2;
    unsigned short* O1F  = (unsigned short*)(base + off); off += 8192 * 2;

    prep_frag<<<384, 256, 0, stream>>>(msg1_W, wPT, 128, 0,   8, 264 * 128, 1, 6 * 16384);
    prep_frag<<<384, 256, 0, stream>>>(msg1_W, wQT, 128, 128, 8, 264 * 128, 1, 6 * 16384);
    prep_frag<<<384, 256, 0, stream>>>(msg2_W, w2F, 128, 0,   8, 128 * 128, 1, 6 * 16384);
    prep_frag<<<384, 256, 0, stream>>>(upd1_W, u1aF, 128, 0,   8, 261 * 128, 1, 6 * 16384);
    prep_frag<<<384, 256, 0, stream>>>(upd1_W, u1bF, 128, 128, 8, 261 * 128, 1, 6 * 16384);
    prep_frag<<<384, 256, 0, stream>>>(upd2_W, u2F, 128, 0,   8, 128 * 128, 1, 6 * 16384);
    prep_frag<<<64, 256, 0, stream>>>(emb_W2, eW2F, 128, 0,   8, 0, 0, 16384);
    prep_frag<<<32, 256, 0, stream>>>(out_W1, O1F, 64, 0,    4, 0, 1, 8192);

    node_init<<<256, 256, 0, stream>>>(inputs, cp, u, posx, posy, mrbuf);
    embed_mfma<<<1024, 256, 0, stream>>>(u, posx, posy, cp, emb_W1, emb_b1, eW2F, emb_b2, f);
    for (int l = 0; l < 6; l++) {
        pqu_kernel<<<1024, 256, 0, stream>>>(f, mrbuf,
            wPT + (size_t)l * 16384, wQT + (size_t)l * 16384,
            msg1_W + (size_t)l * 264 * 128, msg1_b + (size_t)l * 128,
            u, posx, posy, cp, Pn, Qn);
        msg_kernel<<<8192, 256, 0, stream>>>(Pn, Qn,
            w2F + (size_t)l * 16384, msg2_b + (size_t)l * 128, aggF);
        updf_kernel<<<1024, 256, 0, stream>>>(f, mrbuf, aggF,
            u1aF + (size_t)l * 16384, u1bF + (size_t)l * 16384, u2F + (size_t)l * 16384,
            upd1_W + (size_t)l * 261 * 128, upd1_b + (size_t)l * 128,
            upd2_b + (size_t)l * 128, cp, partials);
        finalize_kernel<<<4, 256, 0, stream>>>(partials, mrbuf);
    }
    out_head<<<1024, 256, 0, stream>>>(f, mrbuf, O1F, out_b1, out_W2, out_b2, u, out);
}

// Round 5
// 795.185 us; speedup vs baseline: 4.2504x; 1.4489x over previous
//
#include <hip/hip_runtime.h>
#include <hip/hip_bf16.h>
#include <math.h>

#define NNODE 65536
#define NBAT  16384
#define NP    5
#define DT    0.1f
#define EPS   1e-5f

typedef __attribute__((ext_vector_type(8))) short short8;
typedef __attribute__((ext_vector_type(4))) float floatx4;

union S8U { short8 s; unsigned int u[4]; };

// fast swish: x * rcp(1+e^-x); rcp approx err ~1e-7 — invisible at bf16
__device__ __forceinline__ float swishf(float x) {
    return x * __builtin_amdgcn_rcpf(1.f + __expf(-x));
}
__device__ __forceinline__ float asf(unsigned int u) {
    union { unsigned int u; float f; } x; x.u = u; return x.f;
}
__device__ __forceinline__ unsigned short f2b(float f) {
    union { float f; unsigned int u; } x; x.f = f;
    unsigned int r = x.u + 0x7fff + ((x.u >> 16) & 1);
    return (unsigned short)(r >> 16);
}
__device__ __forceinline__ unsigned int pk2(float a, float b) {
    __hip_bfloat162 h = __float22bfloat162_rn(make_float2(a, b));
    union { __hip_bfloat162 h; unsigned int u; } x; x.h = h; return x.u;
}

// padded fragment chunk offset (in shorts)
#define CHP(w, g, r15) ((((w) * 272) + (g) * 17 + (r15)) * 8)

// ---------- weight prep: fp32 [L][rows][ldn] -> bf16 fragment-linear ----------
__global__ __launch_bounds__(256) void prep_frag(
    const float* __restrict__ src, unsigned short* __restrict__ dst,
    int ldn, int koff, int NT, int lstride, int perm, int total)
{
    int i = blockIdx.x * 256 + threadIdx.x;
    if (i >= total) return;
    int nper = NT << 11;
    int l = i / nper;
    int r0 = i - l * nper;
    int t = r0 >> 11;
    int ks = (r0 >> 9) & 3;
    int lane = (r0 >> 3) & 63;
    int j = r0 & 7;
    int lm = lane & 15, lq = lane >> 4;
    int p = ks * 32 + lq * 8 + j;
    int k = perm ? ((p & 7) * 16 + (p >> 3)) : p;
    int n = t * 16 + lm;
    dst[i] = f2b(src[(size_t)l * lstride + (size_t)(koff + k) * ldn + n]);
}

// ---------- node scalars + meanrstd identity init ----------
__global__ __launch_bounds__(256) void node_init(
    const float* __restrict__ inp, const float* __restrict__ cp,
    float* __restrict__ u, float* __restrict__ posx, float* __restrict__ posy,
    float* __restrict__ mr)
{
    int n = blockIdx.x * 256 + threadIdx.x;
    int b = n >> 14, r = n & 16383;
    int a = r >> 7, c = r & 127;
    u[n] = inp[b * 3 * NBAT + r];
    posx[n] = (a * (1.f / 127.f)) * cp[b * NP + 1];
    posy[n] = (c * (1.f / 127.f)) * cp[b * NP + 0];
    if (n < 1024) mr[n] = ((n >> 7) & 1) ? 1.f : 0.f;   // mean 0, rstd 1
}

// ---------- build normalized-f A fragments in registers ----------
__device__ __forceinline__ void build_normf_frags(
    const float* __restrict__ f, const float* __restrict__ mr,
    int block0, int b, int w, int lm, int lq, short8* afr)
{
    int row = block0 + w * 16 + lm;
#pragma unroll
    for (int ks = 0; ks < 4; ks++) {
        int po = ks * 32 + lq * 8;
        float4 v0 = *(const float4*)(f + (size_t)row * 128 + po);
        float4 v1 = *(const float4*)(f + (size_t)row * 128 + po + 4);
        float4 m0 = *(const float4*)(mr + b * 256 + po);
        float4 m1 = *(const float4*)(mr + b * 256 + po + 4);
        float4 s0 = *(const float4*)(mr + b * 256 + 128 + po);
        float4 s1 = *(const float4*)(mr + b * 256 + 128 + po + 4);
        S8U o;
        o.u[0] = pk2((v0.x - m0.x) * s0.x, (v0.y - m0.y) * s0.y);
        o.u[1] = pk2((v0.z - m0.z) * s0.z, (v0.w - m0.w) * s0.w);
        o.u[2] = pk2((v1.x - m1.x) * s1.x, (v1.y - m1.y) * s1.y);
        o.u[3] = pk2((v1.z - m1.z) * s1.z, (v1.w - m1.w) * s1.w);
        afr[ks] = o.s;
    }
}

// ---------- embedding: 8 -> 128 (VALU) -> 128 (MFMA); f written p-space fp32 ----------
__global__ __launch_bounds__(256) void embed_mfma(
    const float* __restrict__ u, const float* __restrict__ posx,
    const float* __restrict__ posy, const float* __restrict__ cp,
    const float* __restrict__ W1, const float* __restrict__ b1,
    const unsigned short* __restrict__ W2F, const float* __restrict__ b2,
    float* __restrict__ f)
{
    __shared__ unsigned short lA[4 * 272 * 8];
    __shared__ unsigned short lB[2048 * 8];
    int tid = threadIdx.x;
    int block0 = blockIdx.x * 64;
    {
        int r = tid >> 2, p4 = tid & 3;
        int n = block0 + r;
        int b = n >> 14;
        float e8[8];
        e8[0] = u[n]; e8[1] = posx[n]; e8[2] = posy[n];
#pragma unroll
        for (int p = 0; p < 5; p++) e8[3 + p] = cp[b * NP + p];
        float a32[32];
        const float4* b4 = (const float4*)(b1 + p4 * 32);
#pragma unroll
        for (int q = 0; q < 8; q++) {
            float4 bv = b4[q];
            a32[q * 4 + 0] = bv.x; a32[q * 4 + 1] = bv.y;
            a32[q * 4 + 2] = bv.z; a32[q * 4 + 3] = bv.w;
        }
#pragma unroll
        for (int i = 0; i < 8; i++) {
            const float4* w4 = (const float4*)(W1 + i * 128 + p4 * 32);
            float ev = e8[i];
#pragma unroll
            for (int q = 0; q < 8; q++) {
                float4 wv = w4[q];
                a32[q * 4 + 0] += ev * wv.x; a32[q * 4 + 1] += ev * wv.y;
                a32[q * 4 + 2] += ev * wv.z; a32[q * 4 + 3] += ev * wv.w;
            }
        }
#pragma unroll
        for (int j = 0; j < 4; j++) {
            S8U o;
#pragma unroll
            for (int q = 0; q < 4; q++)
                o.u[q] = pk2(swishf(a32[j * 8 + 2 * q]), swishf(a32[j * 8 + 2 * q + 1]));
            *(short8*)(lA + CHP(r >> 4, p4 * 4 + j, r & 15)) = o.s;
        }
    }
#pragma unroll
    for (int i = 0; i < 8; i++)
        *(short8*)(lB + (tid + i * 256) * 8) = *(const short8*)(W2F + (tid + i * 256) * 8);
    __syncthreads();
    int w = tid >> 6, lane = tid & 63, lm = lane & 15, lq = lane >> 4;
    floatx4 acc[8];
#pragma unroll
    for (int t = 0; t < 8; t++) acc[t] = (floatx4)(0.f);
#pragma unroll
    for (int ks = 0; ks < 4; ks++) {
        short8 a = *(const short8*)(lA + CHP(w, ks * 4 + lq, lm));
#pragma unroll
        for (int t = 0; t < 8; t++) {
            short8 bf = *(const short8*)(lB + ((t * 4 + ks) * 64 + lane) * 8);
            acc[t] = __builtin_amdgcn_mfma_f32_16x16x32_bf16(a, bf, acc[t], 0, 0, 0);
        }
    }
    float bias2[8];
#pragma unroll
    for (int t = 0; t < 8; t++) bias2[t] = b2[t * 16 + lm];
#pragma unroll
    for (int r = 0; r < 4; r++) {
        int nd = block0 + w * 16 + lq * 4 + r;
        float4 v0, v1;
        v0.x = swishf(acc[0][r] + bias2[0]); v0.y = swishf(acc[1][r] + bias2[1]);
        v0.z = swishf(acc[2][r] + bias2[2]); v0.w = swishf(acc[3][r] + bias2[3]);
        v1.x = swishf(acc[4][r] + bias2[4]); v1.y = swishf(acc[5][r] + bias2[5]);
        v1.z = swishf(acc[6][r] + bias2[6]); v1.w = swishf(acc[7][r] + bias2[7]);
        *(float4*)(f + (size_t)nd * 128 + lm * 8) = v0;
        *(float4*)(f + (size_t)nd * 128 + lm * 8 + 4) = v1;
    }
}

// ---------- pqu: A-frags in regs (norm f); 2 GEMM phases (P, Q); LDS = lB only ----------
__global__ __launch_bounds__(256) void pqu_kernel(
    const float* __restrict__ f, const float* __restrict__ mr,
    const unsigned short* __restrict__ wPT, const unsigned short* __restrict__ wQT,
    const float* __restrict__ mW, const float* __restrict__ mb,
    const float* __restrict__ u, const float* __restrict__ px,
    const float* __restrict__ py, const float* __restrict__ cp,
    unsigned short* __restrict__ Pn, unsigned short* __restrict__ Qn)
{
    __shared__ unsigned short lB[2048 * 8];
    int tid = threadIdx.x;
    int block0 = blockIdx.x * 64;
    int b = block0 >> 14;
    int w = tid >> 6, lane = tid & 63, lm = lane & 15, lq = lane >> 4;

    short8 afr[4];
    build_normf_frags(f, mr, block0, b, w, lm, lq, afr);

    float u4[4], px4[4], py4[4];
#pragma unroll
    for (int r = 0; r < 4; r++) {
        int nd = block0 + w * 16 + lq * 4 + r;
        u4[r] = u[nd]; px4[r] = px[nd]; py4[r] = py[nd];
    }
    float cp5[5];
#pragma unroll
    for (int p = 0; p < 5; p++) cp5[p] = cp[b * NP + p];
    float wu[8], wx[8], wy[8], pt[8];

    for (int ph = 0; ph < 2; ph++) {
        const unsigned short* bsrc = (ph == 0) ? wPT : wQT;
        if (ph) __syncthreads();
#pragma unroll
        for (int i = 0; i < 8; i++)
            *(short8*)(lB + (tid + i * 256) * 8) = *(const short8*)(bsrc + (tid + i * 256) * 8);
        __syncthreads();
        floatx4 acc[8];
#pragma unroll
        for (int t = 0; t < 8; t++) acc[t] = (floatx4)(0.f);
#pragma unroll
        for (int ks = 0; ks < 4; ks++) {
#pragma unroll
            for (int t = 0; t < 8; t++) {
                short8 bf = *(const short8*)(lB + ((t * 4 + ks) * 64 + lane) * 8);
                acc[t] = __builtin_amdgcn_mfma_f32_16x16x32_bf16(afr[ks], bf, acc[t], 0, 0, 0);
            }
        }
        if (ph == 0) {
#pragma unroll
            for (int t = 0; t < 8; t++) {
                int c = t * 16 + lm;
                wu[t] = mW[256 * 128 + c]; wx[t] = mW[257 * 128 + c]; wy[t] = mW[258 * 128 + c];
                float p0 = mb[c];
#pragma unroll
                for (int p = 0; p < 5; p++) p0 += cp5[p] * mW[(259 + p) * 128 + c];
                pt[t] = p0;
            }
#pragma unroll
            for (int r = 0; r < 4; r++) {
                int nd = block0 + w * 16 + lq * 4 + r;
                float v[8];
#pragma unroll
                for (int t = 0; t < 8; t++)
                    v[t] = acc[t][r] + pt[t] + u4[r] * wu[t] + px4[r] * wx[t] + py4[r] * wy[t];
                S8U o;
#pragma unroll
                for (int q = 0; q < 4; q++) o.u[q] = pk2(v[2 * q], v[2 * q + 1]);
                *(short8*)(Pn + (size_t)nd * 128 + lm * 8) = o.s;
            }
        } else {
#pragma unroll
            for (int r = 0; r < 4; r++) {
                int nd = block0 + w * 16 + lq * 4 + r;
                float v[8];
#pragma unroll
                for (int t = 0; t < 8; t++)
                    v[t] = acc[t][r] - (u4[r] * wu[t] + px4[r] * wx[t] + py4[r] * wy[t]);
                S8U o;
#pragma unroll
                for (int q = 0; q < 4; q++) o.u[q] = pk2(v[2 * q], v[2 * q + 1]);
                *(short8*)(Qn + (size_t)nd * 128 + lm * 8) = o.s;
            }
        }
    }
}

// ---------- msg: hidden A-frags built in regs; m = swish(hidden@W2+b2); agg ----------
__global__ __launch_bounds__(256) void msg_kernel(
    const unsigned short* __restrict__ Pn, const unsigned short* __restrict__ Qn,
    const unsigned short* __restrict__ w2F, const float* __restrict__ b2,
    unsigned short* __restrict__ aggF)
{
    __shared__ unsigned short lB[2048 * 8];
    __shared__ unsigned short lAgg[8 * 128];
    int tid = threadIdx.x;
    int base = blockIdx.x * 8;
    int b = base >> 14;
    int a = (base >> 7) & 127;
    int c0 = base & 127;
    int w = tid >> 6, lane = tid & 63, lm = lane & 15, lq = lane >> 4;

    // stage W2 fragments
#pragma unroll
    for (int i = 0; i < 8; i++)
        *(short8*)(lB + (tid + i * 256) * 8) = *(const short8*)(w2F + (tid + i * 256) * 8);

    // build hidden A-fragments in registers: row = w*16+lm, p-slice ks*32+lq*8
    short8 afr[4];
    {
        int tl = lm >> 3, e = lm & 7;
        int idx = (e < 4) ? e : e + 1;
        int dx = idx / 3 - 1, dy = idx % 3 - 1;
        int cc = c0 + w * 2 + tl;
        int na = a + dx, nc = cc + dy;
        bool valid = (na >= 0) & (na < 128) & (nc >= 0) & (nc < 128);
        int t = base + w * 2 + tl;
        int s = valid ? ((b << 14) + (na << 7) + nc) : t;
#pragma unroll
        for (int ks = 0; ks < 4; ks++) {
            int po = ks * 32 + lq * 8;
            S8U pv, qv, o;
            pv.s = *(const short8*)(Pn + (size_t)t * 128 + po);
            qv.s = *(const short8*)(Qn + (size_t)s * 128 + po);
#pragma unroll
            for (int q = 0; q < 4; q++) {
                float pl = asf(pv.u[q] << 16), ph = asf(pv.u[q] & 0xffff0000u);
                float ql = asf(qv.u[q] << 16), qh = asf(qv.u[q] & 0xffff0000u);
                o.u[q] = pk2(swishf(pl + ql), swishf(ph + qh));
            }
            afr[ks] = o.s;
        }
    }
    __syncthreads();

    floatx4 acc[8];
#pragma unroll
    for (int t = 0; t < 8; t++) acc[t] = (floatx4)(0.f);
#pragma unroll
    for (int ks = 0; ks < 4; ks++) {
#pragma unroll
        for (int t = 0; t < 8; t++) {
            short8 bf = *(const short8*)(lB + ((t * 4 + ks) * 64 + lane) * 8);
            acc[t] = __builtin_amdgcn_mfma_f32_16x16x32_bf16(afr[ks], bf, acc[t], 0, 0, 0);
        }
    }

    // epilogue: hoisted per-r masks; swish; sum over 8 edges; /deg
    bool vr[4];
#pragma unroll
    for (int r = 0; r < 4; r++) {
        int row16 = lq * 4 + r;
        int tl2 = row16 >> 3, e = row16 & 7;
        int idx = (e < 4) ? e : e + 1;
        int dx = idx / 3 - 1, dy = idx % 3 - 1;
        int cc = c0 + w * 2 + tl2;
        int na = a + dx, nc = cc + dy;
        vr[r] = (na >= 0) & (na < 128) & (nc >= 0) & (nc < 128);
    }
    float ov[8];
#pragma unroll
    for (int t = 0; t < 8; t++) {
        float bb = b2[t * 16 + lm];
        float s01 = 0.f;
#pragma unroll
        for (int r = 0; r < 4; r++)
            s01 += vr[r] ? swishf(acc[t][r] + bb) : 0.f;
        ov[t] = s01 + __shfl_xor(s01, 16);
    }
    if ((lq & 1) == 0) {
        int tl = w * 2 + (lq >> 1);
        int cc = c0 + tl;
        int deg = (1 + (a > 0) + (a < 127)) * (1 + (cc > 0) + (cc < 127)) - 1;
        float inv = 1.f / (float)deg;
        S8U o;
#pragma unroll
        for (int q = 0; q < 4; q++) o.u[q] = pk2(ov[2 * q] * inv, ov[2 * q + 1] * inv);
        *(short8*)(lAgg + tl * 128 + lm * 8) = o.s;
    }
    __syncthreads();
    if (tid < 128) {
        int row8 = tid >> 4, g = tid & 15;
        int n = base + row8;
        size_t lin = (size_t)(n >> 6) * 1024 + (size_t)(((n & 63) >> 4) * 256 + g * 16 + (n & 15));
        *(short8*)(aggF + lin * 8) = *(const short8*)(lAgg + row8 * 128 + g * 8);
    }
}

// ---------- updf: hid = swish(normf@U1a + agg@U1b + bias); f = norm(f)+swish(hid@U2+c2);
//            per-block partial stats ----------
__global__ __launch_bounds__(256) void updf_kernel(
    float* __restrict__ f, const float* __restrict__ mr,
    const unsigned short* __restrict__ aggF,
    const unsigned short* __restrict__ u1aF, const unsigned short* __restrict__ u1bF,
    const unsigned short* __restrict__ u2F,
    const float* __restrict__ U1, const float* __restrict__ c1,
    const float* __restrict__ c2, const float* __restrict__ cp,
    float* __restrict__ partials)
{
    __shared__ unsigned short lA[4 * 272 * 8];
    __shared__ unsigned short lB[2048 * 8];
    int tid = threadIdx.x;
    int block0 = blockIdx.x * 64;
    int b = block0 >> 14;
    int w = tid >> 6, lane = tid & 63, lm = lane & 15, lq = lane >> 4;

    // phase 1: normf A-frags in regs; lB = U1a
#pragma unroll
    for (int i = 0; i < 8; i++)
        *(short8*)(lB + (tid + i * 256) * 8) = *(const short8*)(u1aF + (tid + i * 256) * 8);
    short8 afr[4];
    build_normf_frags(f, mr, block0, b, w, lm, lq, afr);
    __syncthreads();
    floatx4 acc[8];
#pragma unroll
    for (int t = 0; t < 8; t++) acc[t] = (floatx4)(0.f);
#pragma unroll
    for (int ks = 0; ks < 4; ks++) {
#pragma unroll
        for (int t = 0; t < 8; t++) {
            short8 bf = *(const short8*)(lB + ((t * 4 + ks) * 64 + lane) * 8);
            acc[t] = __builtin_amdgcn_mfma_f32_16x16x32_bf16(afr[ks], bf, acc[t], 0, 0, 0);
        }
    }
    __syncthreads();

    // phase 2: agg A-frags straight from global (fragment-linear); lB = U1b
#pragma unroll
    for (int i = 0; i < 8; i++)
        *(short8*)(lB + (tid + i * 256) * 8) = *(const short8*)(u1bF + (tid + i * 256) * 8);
#pragma unroll
    for (int ks = 0; ks < 4; ks++)
        afr[ks] = *(const short8*)(aggF +
            ((size_t)blockIdx.x * 1024 + w * 256 + (ks * 4 + lq) * 16 + lm) * 8);
    __syncthreads();
#pragma unroll
    for (int ks = 0; ks < 4; ks++) {
#pragma unroll
        for (int t = 0; t < 8; t++) {
            short8 bf = *(const short8*)(lB + ((t * 4 + ks) * 64 + lane) * 8);
            acc[t] = __builtin_amdgcn_mfma_f32_16x16x32_bf16(afr[ks], bf, acc[t], 0, 0, 0);
        }
    }
    __syncthreads();

    // epi1: h = swish(acc + bias) -> lA (padded); lB = U2
    float cp5[5];
#pragma unroll
    for (int p = 0; p < 5; p++) cp5[p] = cp[b * NP + p];
    float pt[8];
#pragma unroll
    for (int t = 0; t < 8; t++) {
        int c = t * 16 + lm;
        float p0 = c1[c];
#pragma unroll
        for (int p = 0; p < 5; p++) p0 += cp5[p] * U1[(256 + p) * 128 + c];
        pt[t] = p0;
    }
#pragma unroll
    for (int r = 0; r < 4; r++) {
        S8U o;
#pragma unroll
        for (int q = 0; q < 4; q++)
            o.u[q] = pk2(swishf(acc[2 * q][r] + pt[2 * q]),
                         swishf(acc[2 * q + 1][r] + pt[2 * q + 1]));
        *(short8*)(lA + CHP(w, lm, lq * 4 + r)) = o.s;
    }
#pragma unroll
    for (int i = 0; i < 8; i++)
        *(short8*)(lB + (tid + i * 256) * 8) = *(const short8*)(u2F + (tid + i * 256) * 8);
    __syncthreads();

    // phase 3: GEMM hid @ U2
#pragma unroll
    for (int t = 0; t < 8; t++) acc[t] = (floatx4)(0.f);
#pragma unroll
    for (int ks = 0; ks < 4; ks++) {
        short8 a = *(const short8*)(lA + CHP(w, ks * 4 + lq, lm));
#pragma unroll
        for (int t = 0; t < 8; t++) {
            short8 bf = *(const short8*)(lB + ((t * 4 + ks) * 64 + lane) * 8);
            acc[t] = __builtin_amdgcn_mfma_f32_16x16x32_bf16(a, bf, acc[t], 0, 0, 0);
        }
    }

    // epi2: fn = norm(f_old) + swish(acc + c2); write f; partial stats
    float c2v[8];
#pragma unroll
    for (int t = 0; t < 8; t++) c2v[t] = c2[t * 16 + lm];
    float4 me0 = *(const float4*)(mr + b * 256 + lm * 8);
    float4 me1 = *(const float4*)(mr + b * 256 + lm * 8 + 4);
    float4 rs0 = *(const float4*)(mr + b * 256 + 128 + lm * 8);
    float4 rs1 = *(const float4*)(mr + b * 256 + 128 + lm * 8 + 4);
    float ssum[8], ssq[8];
#pragma unroll
    for (int t = 0; t < 8; t++) { ssum[t] = 0.f; ssq[t] = 0.f; }
#pragma unroll
    for (int r = 0; r < 4; r++) {
        int nd = block0 + w * 16 + lq * 4 + r;
        float4 f0 = *(const float4*)(f + (size_t)nd * 128 + lm * 8);
        float4 f1 = *(const float4*)(f + (size_t)nd * 128 + lm * 8 + 4);
        float fn[8];
        fn[0] = (f0.x - me0.x) * rs0.x + swishf(acc[0][r] + c2v[0]);
        fn[1] = (f0.y - me0.y) * rs0.y + swishf(acc[1][r] + c2v[1]);
        fn[2] = (f0.z - me0.z) * rs0.z + swishf(acc[2][r] + c2v[2]);
        fn[3] = (f0.w - me0.w) * rs0.w + swishf(acc[3][r] + c2v[3]);
        fn[4] = (f1.x - me1.x) * rs1.x + swishf(acc[4][r] + c2v[4]);
        fn[5] = (f1.y - me1.y) * rs1.y + swishf(acc[5][r] + c2v[5]);
        fn[6] = (f1.z - me1.z) * rs1.z + swishf(acc[6][r] + c2v[6]);
        fn[7] = (f1.w - me1.w) * rs1.w + swishf(acc[7][r] + c2v[7]);
        *(float4*)(f + (size_t)nd * 128 + lm * 8) = make_float4(fn[0], fn[1], fn[2], fn[3]);
        *(float4*)(f + (size_t)nd * 128 + lm * 8 + 4) = make_float4(fn[4], fn[5], fn[6], fn[7]);
#pragma unroll
        for (int t = 0; t < 8; t++) { ssum[t] += fn[t]; ssq[t] += fn[t] * fn[t]; }
    }
#pragma unroll
    for (int t = 0; t < 8; t++) {
        ssum[t] += __shfl_xor(ssum[t], 16); ssum[t] += __shfl_xor(ssum[t], 32);
        ssq[t]  += __shfl_xor(ssq[t], 16);  ssq[t]  += __shfl_xor(ssq[t], 32);
    }
    __syncthreads();
    float* red = (float*)lB;
    if (lq == 0) {
#pragma unroll
        for (int t = 0; t < 8; t++) {
            red[w * 256 + lm * 8 + t] = ssum[t];
            red[w * 256 + 128 + lm * 8 + t] = ssq[t];
        }
    }
    __syncthreads();
    {
        float v = red[tid] + red[256 + tid] + red[512 + tid] + red[768 + tid];
        partials[(size_t)blockIdx.x * 256 + tid] = v;
    }
}

// ---------- finalize: reduce 256 partials per batch -> meanrstd ----------
__global__ __launch_bounds__(256) void finalize_kernel(
    const float* __restrict__ partials, float* __restrict__ mr)
{
    __shared__ float s[256];
    int b = blockIdx.x, tid = threadIdx.x;
    float acc = 0.f;
    const float* p = partials + (size_t)b * 256 * 256 + tid;
#pragma unroll 8
    for (int i = 0; i < 256; i++) acc += p[i * 256];
    s[tid] = acc;
    __syncthreads();
    if (tid < 128) {
        float mean = s[tid] * (1.f / 16384.f);
        float var = s[128 + tid] * (1.f / 16384.f) - mean * mean;
        mr[b * 256 + tid] = mean;
        mr[b * 256 + 128 + tid] = rsqrtf(var + EPS);
    }
}

// ---------- output head: normf A-frags in regs ----------
__global__ __launch_bounds__(256) void out_head(
    const float* __restrict__ f, const float* __restrict__ mr,
    const unsigned short* __restrict__ O1F, const float* __restrict__ ob1,
    const float* __restrict__ O2, const float* __restrict__ ob2,
    const float* __restrict__ u, float* __restrict__ out)
{
    __shared__ unsigned short lB[1024 * 8];
    int tid = threadIdx.x;
    int block0 = blockIdx.x * 64;
    int b = block0 >> 14;
    int w = tid >> 6, lane = tid & 63, lm = lane & 15, lq = lane >> 4;
#pragma unroll
    for (int i = 0; i < 4; i++)
        *(short8*)(lB + (tid + i * 256) * 8) = *(const short8*)(O1F + (tid + i * 256) * 8);
    short8 afr[4];
    build_normf_frags(f, mr, block0, b, w, lm, lq, afr);
    __syncthreads();
    floatx4 acc[4];
#pragma unroll
    for (int t = 0; t < 4; t++) acc[t] = (floatx4)(0.f);
#pragma unroll
    for (int ks = 0; ks < 4; ks++) {
#pragma unroll
        for (int t = 0; t < 4; t++) {
            short8 bf = *(const short8*)(lB + ((t * 4 + ks) * 64 + lane) * 8);
            acc[t] = __builtin_amdgcn_mfma_f32_16x16x32_bf16(afr[ks], bf, acc[t], 0, 0, 0);
        }
    }
    float b1v[4], o2v[4];
#pragma unroll
    for (int t = 0; t < 4; t++) {
        b1v[t] = ob1[t * 16 + lm];
        o2v[t] = O2[t * 16 + lm];
    }
    float ob2v = ob2[0];
#pragma unroll
    for (int r = 0; r < 4; r++) {
        float s = 0.f;
#pragma unroll
        for (int t = 0; t < 4; t++) s += swishf(acc[t][r] + b1v[t]) * o2v[t];
        s += __shfl_xor(s, 1); s += __shfl_xor(s, 2);
        s += __shfl_xor(s, 4); s += __shfl_xor(s, 8);
        if (lm == 0) {
            int nd = block0 + w * 16 + lq * 4 + r;
            out[nd] = u[nd] + DT * (s + ob2v);
        }
    }
}

extern "C" void kernel_launch(void* const* d_in, const int* in_sizes, int n_in,
                              void* d_out, int out_size, void* d_ws, size_t ws_size,
                              hipStream_t stream)
{
    const float* inputs = (const float*)d_in[0];
    const float* cp     = (const float*)d_in[1];
    const float* emb_W1 = (const float*)d_in[3];
    const float* emb_b1 = (const float*)d_in[4];
    const float* emb_W2 = (const float*)d_in[5];
    const float* emb_b2 = (const float*)d_in[6];
    const float* msg1_W = (const float*)d_in[7];
    const float* msg1_b = (const float*)d_in[8];
    const float* msg2_W = (const float*)d_in[9];
    const float* msg2_b = (const float*)d_in[10];
    const float* upd1_W = (const float*)d_in[11];
    const float* upd1_b = (const float*)d_in[12];
    const float* upd2_W = (const float*)d_in[13];
    const float* upd2_b = (const float*)d_in[14];
    const float* out_W1 = (const float*)d_in[15];
    const float* out_b1 = (const float*)d_in[16];
    const float* out_W2 = (const float*)d_in[17];
    const float* out_b2 = (const float*)d_in[18];
    float* out = (float*)d_out;

    char* base = (char*)d_ws;
    size_t off = 0;
    float* f     = (float*)(base + off); off += (size_t)NNODE * 128 * 4;
    unsigned short* Pn   = (unsigned short*)(base + off); off += (size_t)NNODE * 128 * 2;
    unsigned short* Qn   = (unsigned short*)(base + off); off += (size_t)NNODE * 128 * 2;
    unsigned short* aggF = (unsigned short*)(base + off); off += (size_t)NNODE * 128 * 2;
    float* u    = (float*)(base + off); off += NNODE * 4;
    float* posx = (float*)(base + off); off += NNODE * 4;
    float* posy = (float*)(base + off); off += NNODE * 4;
    float* partials = (float*)(base + off); off += 1024 * 256 * 4;
    float* mrbuf = (float*)(base + off); off += 1024 * 4;
    unsigned short* wPT  = (unsigned short*)(base + off); off += 6 * 16384 * 2;
    unsigned short* wQT  = (unsigned short*)(base + off); off += 6 * 16384 * 2;
    unsigned short* w2F  = (unsigned short*)(base + off); off += 6 * 16384 * 2;
    unsigned short* u1aF = (unsigned short*)(base + off); off += 6 * 16384 * 2;
    unsigned short* u1bF = (unsigned short*)(base + off); off += 6 * 16384 * 2;
    unsigned short* u2F  = (unsigned short*)(base + off); off += 6 * 16384 * 2;
    unsigned short* eW2F = (unsigned short*)(base + off); off += 16384 * 2;
    unsigned short* O1F  = (unsigned short*)(base + off); off += 8192 * 2;

    prep_frag<<<384, 256, 0, stream>>>(msg1_W, wPT, 128, 0,   8, 264 * 128, 1, 6 * 16384);
    prep_frag<<<384, 256, 0, stream>>>(msg1_W, wQT, 128, 128, 8, 264 * 128, 1, 6 * 16384);
    prep_frag<<<384, 256, 0, stream>>>(msg2_W, w2F, 128, 0,   8, 128 * 128, 1, 6 * 16384);
    prep_frag<<<384, 256, 0, stream>>>(upd1_W, u1aF, 128, 0,   8, 261 * 128, 1, 6 * 16384);
    prep_frag<<<384, 256, 0, stream>>>(upd1_W, u1bF, 128, 128, 8, 261 * 128, 1, 6 * 16384);
    prep_frag<<<384, 256, 0, stream>>>(upd2_W, u2F, 128, 0,   8, 128 * 128, 1, 6 * 16384);
    prep_frag<<<64, 256, 0, stream>>>(emb_W2, eW2F, 128, 0,   8, 0, 0, 16384);
    prep_frag<<<32, 256, 0, stream>>>(out_W1, O1F, 64, 0,    4, 0, 1, 8192);

    node_init<<<256, 256, 0, stream>>>(inputs, cp, u, posx, posy, mrbuf);
    embed_mfma<<<1024, 256, 0, stream>>>(u, posx, posy, cp, emb_W1, emb_b1, eW2F, emb_b2, f);
    for (int l = 0; l < 6; l++) {
        pqu_kernel<<<1024, 256, 0, stream>>>(f, mrbuf,
            wPT + (size_t)l * 16384, wQT + (size_t)l * 16384,
            msg1_W + (size_t)l * 264 * 128, msg1_b + (size_t)l * 128,
            u, posx, posy, cp, Pn, Qn);
        msg_kernel<<<8192, 256, 0, stream>>>(Pn, Qn,
            w2F + (size_t)l * 16384, msg2_b + (size_t)l * 128, aggF);
        updf_kernel<<<1024, 256, 0, stream>>>(f, mrbuf, aggF,
            u1aF + (size_t)l * 16384, u1bF + (size_t)l * 16384, u2F + (size_t)l * 16384,
            upd1_W + (size_t)l * 261 * 128, upd1_b + (size_t)l * 128,
            upd2_b + (size_t)l * 128, cp, partials);
        finalize_kernel<<<4, 256, 0, stream>>>(partials, mrbuf);
    }
    out_head<<<1024, 256, 0, stream>>>(f, mrbuf, O1F, out_b1, out_W2, out_b2, u, out);
}